// Round 5
// baseline (178.579 us; speedup 1.0000x reference)
//
#include <hip/hip_runtime.h>
#include <hip/hip_bf16.h>

// Problem dims (fixed): B=2, M=L=2048, H=1024, K_HEADS=16, D=64
// All inputs/output are FLOAT32; compute in bf16 MFMA with f32 accumulation.
// Algebra: softmax branch is dead; out = Q (K^T V) blockdiag, folded as
//   T = K^T V (per head, 64x64) ; W2[n][h*64+dp] = sum_d Wo[n][h*64+d] T[h][dp][d]
//   final = Q @ W2^T   (one NT GEMM per batch)
// GEMMs use 32x32x16 bf16 MFMA (m119: 2495 TF vs 2176 for 16x16x32).
#define BB 2
#define MM 2048
#define HH 1024
#define KH 16

typedef short s16x8 __attribute__((ext_vector_type(8)));
typedef float f32x4 __attribute__((ext_vector_type(4)));
typedef float f32x16 __attribute__((ext_vector_type(16)));

#define GLOBAL_AS __attribute__((address_space(1)))
#define LDS_AS    __attribute__((address_space(3)))

__device__ __forceinline__ void async_copy16(const void* g, void* l) {
    __builtin_amdgcn_global_load_lds((const GLOBAL_AS void*)g, (LDS_AS void*)l, 16, 0, 0);
}

struct __align__(8) bf16x4_t { __hip_bfloat16 x, y, z, w; };

// ---------------------------------------------------------------------------
// fused fp32 -> bf16 conversion + Sbuf zeroing: grid (4096, 7)
// ---------------------------------------------------------------------------
__global__ __launch_bounds__(256) void cvt7(
    const float* __restrict__ s0, const float* __restrict__ s1,
    const float* __restrict__ s2, const float* __restrict__ s3,
    const float* __restrict__ s4, const float* __restrict__ s5,
    __hip_bfloat16* __restrict__ d0, __hip_bfloat16* __restrict__ d1,
    __hip_bfloat16* __restrict__ d2, __hip_bfloat16* __restrict__ d3,
    __hip_bfloat16* __restrict__ d4, __hip_bfloat16* __restrict__ d5,
    float* __restrict__ Sz)
{
    const int seg = blockIdx.y;
    const int i = (blockIdx.x * 256 + threadIdx.x) * 4;
    if (seg == 6) {
        if (i + 3 < BB * KH * 64 * 64) {
            float4 z = {0.f, 0.f, 0.f, 0.f};
            *(float4*)(Sz + i) = z;
        }
        return;
    }
    const float* src;
    __hip_bfloat16* dst;
    int n;
    switch (seg) {
        case 0: src = s0; dst = d0; n = BB * MM * HH; break;
        case 1: src = s1; dst = d1; n = BB * MM * HH; break;
        case 2: src = s2; dst = d2; n = HH * HH; break;
        case 3: src = s3; dst = d3; n = HH * HH; break;
        case 4: src = s4; dst = d4; n = HH * HH; break;
        default: src = s5; dst = d5; n = HH * HH; break;
    }
    if (i + 3 < n) {
        const float4 v = *(const float4*)(src + i);
        bf16x4_t o;
        o.x = __float2bfloat16(v.x);
        o.y = __float2bfloat16(v.y);
        o.z = __float2bfloat16(v.z);
        o.w = __float2bfloat16(v.w);
        *(bf16x4_t*)(dst + i) = o;
    }
}

// ---------------------------------------------------------------------------
// NT GEMM 128x128 body, 32x32x16 MFMA: C[m,n] = sum_k A[m,k]*Bm[n,k], Kdim=HH
// Wave tile 64x64 = 2x2 of 32x32. A/B frag: row = lane&31, k = (lane>>5)*8+j.
// C/D: col = lane&31, row = (reg&3) + 8*(reg>>2) + 4*(lane>>5)  [m74/m101]
// ---------------------------------------------------------------------------
__device__ __forceinline__ void store_c(__hip_bfloat16* C, size_t idx, float v) {
    C[idx] = __float2bfloat16(v);
}
__device__ __forceinline__ void store_c(float* C, size_t idx, float v) { C[idx] = v; }

template <typename OutT>
__device__ __forceinline__ void gemm_nt_body32(
    const __hip_bfloat16* __restrict__ A,
    const __hip_bfloat16* __restrict__ Bm,
    OutT* __restrict__ C,
    __hip_bfloat16* As, __hip_bfloat16* Bs,
    int m0, int n0)
{
    const int t    = threadIdx.x;
    const int lane = t & 63;
    const int wave = t >> 6;

    // staging (unchanged from m97 structure): chunk c = 16 rows x 32 cols
    const int lr = lane >> 2;
    const int lc = (lane & 3) * 8;

    const int wm = (wave >> 1) * 64;
    const int wn = (wave & 1) * 64;
    const int fm = lane & 31;            // fragment row within 32-tile
    const int fk = (lane >> 5) * 8;      // k sub-offset

    f32x16 acc[2][2] = {};

    for (int k0 = 0; k0 < HH; k0 += 32) {
        __syncthreads();
#pragma unroll
        for (int i = 0; i < 2; ++i) {
            const int c = wave * 2 + i;
            async_copy16(A  + (size_t)(m0 + c * 16 + lr) * HH + (k0 + lc), As + c * 512);
            async_copy16(Bm + (size_t)(n0 + c * 16 + lr) * HH + (k0 + lc), Bs + c * 512);
        }
        __syncthreads();

#pragma unroll
        for (int ks = 0; ks < 32; ks += 16) {
            s16x8 af[2], bf[2];
#pragma unroll
            for (int mi = 0; mi < 2; ++mi)
                af[mi] = *(const s16x8*)(As + (wm + mi * 32 + fm) * 32 + ks + fk);
#pragma unroll
            for (int ni = 0; ni < 2; ++ni)
                bf[ni] = *(const s16x8*)(Bs + (wn + ni * 32 + fm) * 32 + ks + fk);
#pragma unroll
            for (int mi = 0; mi < 2; ++mi)
#pragma unroll
                for (int ni = 0; ni < 2; ++ni)
                    acc[mi][ni] = __builtin_amdgcn_mfma_f32_32x32x16_bf16(
                        af[mi], bf[ni], acc[mi][ni], 0, 0, 0);
        }
    }

    const int ec = lane & 31;
    const int eb = (lane >> 5) * 4;
#pragma unroll
    for (int mi = 0; mi < 2; ++mi)
#pragma unroll
        for (int ni = 0; ni < 2; ++ni)
#pragma unroll
            for (int r = 0; r < 16; ++r) {
                const int m = m0 + wm + mi * 32 + (r & 3) + 8 * (r >> 2) + eb;
                const int n = n0 + wn + ni * 32 + ec;
                store_c(C, (size_t)m * HH + n, acc[mi][ni][r]);
            }
}

// fused Q/K/V projections: grid (32, 8, 3) = 768 blocks (3/CU)
__global__ __launch_bounds__(256) void gemm_qkv(
    const __hip_bfloat16* __restrict__ hb,  const __hip_bfloat16* __restrict__ hcb,
    const __hip_bfloat16* __restrict__ wq,  const __hip_bfloat16* __restrict__ wk,
    const __hip_bfloat16* __restrict__ wv,
    __hip_bfloat16* __restrict__ Q, __hip_bfloat16* __restrict__ K,
    __hip_bfloat16* __restrict__ V)
{
    __shared__ __align__(16) __hip_bfloat16 As[128 * 32];
    __shared__ __align__(16) __hip_bfloat16 Bs[128 * 32];
    const int z = blockIdx.z;
    const __hip_bfloat16* A  = (z == 0) ? hb : hcb;
    const __hip_bfloat16* Bm = (z == 0) ? wq : (z == 1) ? wk : wv;
    __hip_bfloat16* C        = (z == 0) ? Q  : (z == 1) ? K  : V;
    gemm_nt_body32(A, Bm, C, As, Bs, blockIdx.x * 128, blockIdx.y * 128);
}

// ---------------------------------------------------------------------------
// final GEMM, 64x128 tile, 32x32x16 MFMA: out[b] = Q[b] @ W2[b]^T (fp32)
// grid (32, 8, 2) = 512 blocks; wave w: m-tiles {0,32}, n-cols [w*32, w*32+32)
// ---------------------------------------------------------------------------
__global__ __launch_bounds__(256) void gemm_final(
    const __hip_bfloat16* __restrict__ Qg, const __hip_bfloat16* __restrict__ W2g,
    float* __restrict__ outg)
{
    __shared__ __align__(16) __hip_bfloat16 As[64 * 32];    // 4 KB
    __shared__ __align__(16) __hip_bfloat16 Bs[128 * 32];   // 8 KB

    const int b = blockIdx.z;
    const __hip_bfloat16* A  = Qg  + (size_t)b * MM * HH;
    const __hip_bfloat16* Bm = W2g + (size_t)b * HH * HH;
    float* C                 = outg + (size_t)b * MM * HH;
    const int m0 = blockIdx.x * 64;
    const int n0 = blockIdx.y * 128;

    const int t    = threadIdx.x;
    const int lane = t & 63;
    const int wave = t >> 6;
    const int lr = lane >> 2;
    const int lc = (lane & 3) * 8;
    const int fm = lane & 31;
    const int fk = (lane >> 5) * 8;

    f32x16 acc[2] = {};

    for (int k0 = 0; k0 < HH; k0 += 32) {
        __syncthreads();
        async_copy16(A  + (size_t)(m0 + wave * 16 + lr) * HH + (k0 + lc),
                     As + wave * 512);
        async_copy16(Bm + (size_t)(n0 + (2 * wave) * 16 + lr) * HH + (k0 + lc),
                     Bs + (2 * wave) * 512);
        async_copy16(Bm + (size_t)(n0 + (2 * wave + 1) * 16 + lr) * HH + (k0 + lc),
                     Bs + (2 * wave + 1) * 512);
        __syncthreads();

#pragma unroll
        for (int ks = 0; ks < 32; ks += 16) {
            s16x8 af[2], bf;
#pragma unroll
            for (int mi = 0; mi < 2; ++mi)
                af[mi] = *(const s16x8*)(As + (mi * 32 + fm) * 32 + ks + fk);
            bf = *(const s16x8*)(Bs + (wave * 32 + fm) * 32 + ks + fk);
#pragma unroll
            for (int mi = 0; mi < 2; ++mi)
                acc[mi] = __builtin_amdgcn_mfma_f32_32x32x16_bf16(
                    af[mi], bf, acc[mi], 0, 0, 0);
        }
    }

    const int ec = lane & 31;
    const int eb = (lane >> 5) * 4;
#pragma unroll
    for (int mi = 0; mi < 2; ++mi)
#pragma unroll
        for (int r = 0; r < 16; ++r) {
            const int m = m0 + mi * 32 + (r & 3) + 8 * (r >> 2) + eb;
            const int n = n0 + wave * 32 + ec;
            C[(size_t)m * HH + n] = acc[mi][r];
        }
}

// ---------------------------------------------------------------------------
// T[b,h,d1,d2] += sum_l K[b,l,h*64+d1] * V[b,l,h*64+d2]  via 16x16x32 MFMA.
// grid (16, KH, BB) = 512 blocks.
// ---------------------------------------------------------------------------
#define CH 128   // l-rows per block
#define LP 136   // padded LDS leading dim (elements)

__global__ __launch_bounds__(256) void kv_outer_mfma(
    const __hip_bfloat16* __restrict__ Km,
    const __hip_bfloat16* __restrict__ Vm,
    float* __restrict__ S)
{
    __shared__ __align__(16) __hip_bfloat16 Kt[64 * LP];  // [d1][l]
    __shared__ __align__(16) __hip_bfloat16 Vt[64 * LP];  // [d2][l]

    const int t = threadIdx.x, head = blockIdx.y, b = blockIdx.z;
    const int l0 = blockIdx.x * CH;

    const int r  = t & 127;
    const int cb = (t >> 7) * 8;
    const size_t gbase = (size_t)(b * MM + l0 + r) * HH + head * 64;
#pragma unroll
    for (int u = 0; u < 4; ++u) {
        const int c8 = cb + u * 16;
        const s16x8 kv = *(const s16x8*)(Km + gbase + c8);
        const s16x8 vv = *(const s16x8*)(Vm + gbase + c8);
#pragma unroll
        for (int j = 0; j < 8; ++j) {
            Kt[(c8 + j) * LP + r] = ((const __hip_bfloat16*)&kv)[j];
            Vt[(c8 + j) * LP + r] = ((const __hip_bfloat16*)&vv)[j];
        }
    }
    __syncthreads();

    const int wave = t >> 6, lane = t & 63;
    const int fr = lane & 15;
    const int fq = (lane >> 4) * 8;
    const int wm = wave * 16;

    f32x4 acc[4] = {};
    for (int kk = 0; kk < CH; kk += 32) {
        const s16x8 af = *(const s16x8*)(Kt + (wm + fr) * LP + kk + fq);
        s16x8 bf[4];
#pragma unroll
        for (int nj = 0; nj < 4; ++nj)
            bf[nj] = *(const s16x8*)(Vt + (nj * 16 + fr) * LP + kk + fq);
#pragma unroll
        for (int nj = 0; nj < 4; ++nj)
            acc[nj] = __builtin_amdgcn_mfma_f32_16x16x32_bf16(af, bf[nj], acc[nj], 0, 0, 0);
    }

    float* Sg = S + ((size_t)b * KH + head) * 4096;
    const int er = (lane >> 4) * 4;
    const int ec = lane & 15;
#pragma unroll
    for (int nj = 0; nj < 4; ++nj)
#pragma unroll
        for (int rr = 0; rr < 4; ++rr)
            atomicAdd(&Sg[(wm + er + rr) * 64 + nj * 16 + ec], acc[nj][rr]);
}

// ---------------------------------------------------------------------------
// W2[b][n][h*64+dp] = sum_d Wo[n][h*64+d] * T[b,h,dp,d]   (bf16 out)
// grid (8, KH, BB), block 256
// ---------------------------------------------------------------------------
__global__ __launch_bounds__(256) void w2_fold(
    const __hip_bfloat16* __restrict__ Wo,
    const float* __restrict__ S,
    __hip_bfloat16* __restrict__ W2)
{
    __shared__ float Sl[64 * 68];
    __shared__ float Wl[128 * 68];
    const int t = threadIdx.x, head = blockIdx.y, b = blockIdx.z;
    const int n0 = blockIdx.x * 128;

    const float* Sg = S + ((size_t)b * KH + head) * 4096;
    for (int idx = t; idx < 4096; idx += 256) {
        const int dp = idx >> 6, d = idx & 63;
        Sl[d * 68 + dp] = Sg[idx];
    }
    for (int idx = t; idx < 1024; idx += 256) {
        const int r = idx >> 3, c8 = (idx & 7) * 8;
        s16x8 wv = *(const s16x8*)(Wo + (size_t)(n0 + r) * HH + head * 64 + c8);
#pragma unroll
        for (int j = 0; j < 8; ++j) {
            __hip_bfloat16 wb = *(((const __hip_bfloat16*)&wv) + j);
            Wl[r * 68 + c8 + j] = __bfloat162float(wb);
        }
    }
    __syncthreads();

    const int dpb = (t & 15) * 4;
    const int ng  = t >> 4;
    float acc[8][4] = {};
    for (int d0 = 0; d0 < 64; d0 += 4) {
        f32x4 sv[4];
#pragma unroll
        for (int r = 0; r < 4; ++r)
            sv[r] = *(const f32x4*)(Sl + (d0 + r) * 68 + dpb);
#pragma unroll
        for (int i = 0; i < 8; ++i) {
            const f32x4 wv = *(const f32x4*)(Wl + (ng + 16 * i) * 68 + d0);
#pragma unroll
            for (int r = 0; r < 4; ++r)
#pragma unroll
                for (int j = 0; j < 4; ++j)
                    acc[i][j] += wv[r] * sv[r][j];
        }
    }

#pragma unroll
    for (int i = 0; i < 8; ++i) {
        bf16x4_t o;
        o.x = __float2bfloat16(acc[i][0]);
        o.y = __float2bfloat16(acc[i][1]);
        o.z = __float2bfloat16(acc[i][2]);
        o.w = __float2bfloat16(acc[i][3]);
        *(bf16x4_t*)(W2 + (size_t)b * HH * HH + (size_t)(n0 + ng + 16 * i) * HH
                     + head * 64 + dpb) = o;
    }
}

// ---------------------------------------------------------------------------
extern "C" void kernel_launch(void* const* d_in, const int* in_sizes, int n_in,
                              void* d_out, int out_size, void* d_ws, size_t ws_size,
                              hipStream_t stream) {
    const float* h_f  = (const float*)d_in[0];
    const float* hc_f = (const float*)d_in[1];
    // d_in[2] = key_pe: DEAD (softmax result unused by reference output)
    const float* Wq_f = (const float*)d_in[3];
    const float* Wk_f = (const float*)d_in[4];
    const float* Wv_f = (const float*)d_in[5];
    const float* Wo_f = (const float*)d_in[6];
    float* out = (float*)d_out;

    const size_t act_b = (size_t)BB * MM * HH * 2;  // 8 MB
    const size_t w_b   = (size_t)HH * HH * 2;       // 2 MB
    char* ws = (char*)d_ws;
    __hip_bfloat16* hb   = (__hip_bfloat16*)(ws);
    __hip_bfloat16* hcb  = (__hip_bfloat16*)(ws + act_b);
    __hip_bfloat16* wqb  = (__hip_bfloat16*)(ws + 2 * act_b);
    __hip_bfloat16* wkb  = (__hip_bfloat16*)(ws + 2 * act_b + w_b);
    __hip_bfloat16* wvb  = (__hip_bfloat16*)(ws + 2 * act_b + 2 * w_b);
    __hip_bfloat16* wob  = (__hip_bfloat16*)(ws + 2 * act_b + 3 * w_b);
    __hip_bfloat16* Qbuf = (__hip_bfloat16*)(ws + 2 * act_b + 4 * w_b);
    __hip_bfloat16* Kbuf = (__hip_bfloat16*)(ws + 3 * act_b + 4 * w_b);
    __hip_bfloat16* Vbuf = (__hip_bfloat16*)(ws + 4 * act_b + 4 * w_b);
    float*          Sbuf = (float*)(ws + 5 * act_b + 4 * w_b);            // 512 KB
    __hip_bfloat16* W2   = (__hip_bfloat16*)(ws + 5 * act_b + 4 * w_b + (size_t)512 * 1024);

    const dim3 blk(256);

    // 0: fp32->bf16 converts + Sbuf zeroing in one dispatch
    cvt7<<<dim3(4096, 7), blk, 0, stream>>>(h_f, hc_f, Wq_f, Wk_f, Wv_f, Wo_f,
                                            hb, hcb, wqb, wkb, wvb, wob, Sbuf);

    // 1: fused Q/K/V projections (32x32x16 MFMA)
    gemm_qkv<<<dim3(32, 8, 3), blk, 0, stream>>>(hb, hcb, wqb, wkb, wvb,
                                                 Qbuf, Kbuf, Vbuf);

    // 2: T = K^T V per head (MFMA, atomic partials into zeroed Sbuf)
    kv_outer_mfma<<<dim3(MM / CH, KH, BB), blk, 0, stream>>>(Kbuf, Vbuf, Sbuf);

    // 3: W2 = blockdiag(T) folded into Wo
    w2_fold<<<dim3(8, KH, BB), blk, 0, stream>>>(wob, Sbuf, W2);

    // 4: final = Q @ W2^T (fp32 out, 512 blocks, 32x32x16 MFMA)
    gemm_final<<<dim3(32, 8, 2), blk, 0, stream>>>(Qbuf, W2, out);
}

// Round 6
// 174.197 us; speedup vs baseline: 1.0252x; 1.0252x over previous
//
#include <hip/hip_runtime.h>
#include <hip/hip_bf16.h>

// Problem dims (fixed): B=2, M=L=2048, H=1024, K_HEADS=16, D=64
// All inputs/output are FLOAT32; compute in bf16 MFMA with f32 accumulation.
// Algebra: softmax branch is dead; out = Q (K^T V) blockdiag, folded as
//   T = K^T V (per head, 64x64) ; W2[n][h*64+dp] = sum_d Wo[n][h*64+d] T[h][dp][d]
//   final = Q @ W2^T   (one NT GEMM per batch)
// GEMMs: 32x32x16 bf16 MFMA with XOR-swizzled LDS k-groups (bank-conflict-free:
// round-5 measured 9.4M SQ_LDS_BANK_CONFLICT from the unswizzled 32-row layout).
#define BB 2
#define MM 2048
#define HH 1024
#define KH 16

typedef short s16x8 __attribute__((ext_vector_type(8)));
typedef float f32x4 __attribute__((ext_vector_type(4)));
typedef float f32x16 __attribute__((ext_vector_type(16)));

#define GLOBAL_AS __attribute__((address_space(1)))
#define LDS_AS    __attribute__((address_space(3)))

__device__ __forceinline__ void async_copy16(const void* g, void* l) {
    __builtin_amdgcn_global_load_lds((const GLOBAL_AS void*)g, (LDS_AS void*)l, 16, 0, 0);
}

struct __align__(8) bf16x4_t { __hip_bfloat16 x, y, z, w; };

// ---------------------------------------------------------------------------
// fused fp32 -> bf16 conversion + Sbuf zeroing: grid (4096, 7)
// ---------------------------------------------------------------------------
__global__ __launch_bounds__(256) void cvt7(
    const float* __restrict__ s0, const float* __restrict__ s1,
    const float* __restrict__ s2, const float* __restrict__ s3,
    const float* __restrict__ s4, const float* __restrict__ s5,
    __hip_bfloat16* __restrict__ d0, __hip_bfloat16* __restrict__ d1,
    __hip_bfloat16* __restrict__ d2, __hip_bfloat16* __restrict__ d3,
    __hip_bfloat16* __restrict__ d4, __hip_bfloat16* __restrict__ d5,
    float* __restrict__ Sz)
{
    const int seg = blockIdx.y;
    const int i = (blockIdx.x * 256 + threadIdx.x) * 4;
    if (seg == 6) {
        if (i + 3 < BB * KH * 64 * 64) {
            float4 z = {0.f, 0.f, 0.f, 0.f};
            *(float4*)(Sz + i) = z;
        }
        return;
    }
    const float* src;
    __hip_bfloat16* dst;
    int n;
    switch (seg) {
        case 0: src = s0; dst = d0; n = BB * MM * HH; break;
        case 1: src = s1; dst = d1; n = BB * MM * HH; break;
        case 2: src = s2; dst = d2; n = HH * HH; break;
        case 3: src = s3; dst = d3; n = HH * HH; break;
        case 4: src = s4; dst = d4; n = HH * HH; break;
        default: src = s5; dst = d5; n = HH * HH; break;
    }
    if (i + 3 < n) {
        const float4 v = *(const float4*)(src + i);
        bf16x4_t o;
        o.x = __float2bfloat16(v.x);
        o.y = __float2bfloat16(v.y);
        o.z = __float2bfloat16(v.z);
        o.w = __float2bfloat16(v.w);
        *(bf16x4_t*)(dst + i) = o;
    }
}

// ---------------------------------------------------------------------------
// NT GEMM 128x128 body, 32x32x16 MFMA, swizzled LDS k-groups.
// LDS(row, pos) holds global k-group pos ^ ((row>>1)&3); staging lane fetches
// global group (lane&3) ^ ((lane>>3)&3) so its fixed LDS slot gets the right
// data (chunk bases are multiples of 16 rows, so (row>>1)&3 = (lr>>1)&3).
// Frag read for logical group g at row fm: pos = g ^ ((fm>>1)&3).
// C/D: col = lane&31, row = (reg&3) + 8*(reg>>2) + 4*(lane>>5)  [m74/m101]
// ---------------------------------------------------------------------------
__device__ __forceinline__ void store_c(__hip_bfloat16* C, size_t idx, float v) {
    C[idx] = __float2bfloat16(v);
}
__device__ __forceinline__ void store_c(float* C, size_t idx, float v) { C[idx] = v; }

template <typename OutT>
__device__ __forceinline__ void gemm_nt_body32(
    const __hip_bfloat16* __restrict__ A,
    const __hip_bfloat16* __restrict__ Bm,
    OutT* __restrict__ C,
    __hip_bfloat16* As, __hip_bfloat16* Bs,
    int m0, int n0)
{
    const int t    = threadIdx.x;
    const int lane = t & 63;
    const int wave = t >> 6;

    // staging: chunk c = 16 rows x 32 cols; lane row lr, SWIZZLED col group
    const int lr = lane >> 2;
    const int lc = (((lane & 3) ^ ((lane >> 3) & 3)) * 8);

    const int wm = (wave >> 1) * 64;
    const int wn = (wave & 1) * 64;
    const int fm = lane & 31;            // fragment row within 32-tile
    const int swr = (lane >> 1) & 3;     // (fm>>1)&3 — row's swizzle key
    const int ghi = lane >> 5;           // k-group high bit from lane

    f32x16 acc[2][2] = {};

    for (int k0 = 0; k0 < HH; k0 += 32) {
        __syncthreads();
#pragma unroll
        for (int i = 0; i < 2; ++i) {
            const int c = wave * 2 + i;
            async_copy16(A  + (size_t)(m0 + c * 16 + lr) * HH + (k0 + lc), As + c * 512);
            async_copy16(Bm + (size_t)(n0 + c * 16 + lr) * HH + (k0 + lc), Bs + c * 512);
        }
        __syncthreads();

#pragma unroll
        for (int ks = 0; ks < 32; ks += 16) {
            const int pos = ((((ks >> 3) + ghi) ^ swr) * 8);
            s16x8 af[2], bf[2];
#pragma unroll
            for (int mi = 0; mi < 2; ++mi)
                af[mi] = *(const s16x8*)(As + (wm + mi * 32 + fm) * 32 + pos);
#pragma unroll
            for (int ni = 0; ni < 2; ++ni)
                bf[ni] = *(const s16x8*)(Bs + (wn + ni * 32 + fm) * 32 + pos);
#pragma unroll
            for (int mi = 0; mi < 2; ++mi)
#pragma unroll
                for (int ni = 0; ni < 2; ++ni)
                    acc[mi][ni] = __builtin_amdgcn_mfma_f32_32x32x16_bf16(
                        af[mi], bf[ni], acc[mi][ni], 0, 0, 0);
        }
    }

    const int ec = lane & 31;
    const int eb = (lane >> 5) * 4;
#pragma unroll
    for (int mi = 0; mi < 2; ++mi)
#pragma unroll
        for (int ni = 0; ni < 2; ++ni)
#pragma unroll
            for (int r = 0; r < 16; ++r) {
                const int m = m0 + wm + mi * 32 + (r & 3) + 8 * (r >> 2) + eb;
                const int n = n0 + wn + ni * 32 + ec;
                store_c(C, (size_t)m * HH + n, acc[mi][ni][r]);
            }
}

// fused Q/K/V projections: grid (32, 8, 3) = 768 blocks (3/CU)
__global__ __launch_bounds__(256) void gemm_qkv(
    const __hip_bfloat16* __restrict__ hb,  const __hip_bfloat16* __restrict__ hcb,
    const __hip_bfloat16* __restrict__ wq,  const __hip_bfloat16* __restrict__ wk,
    const __hip_bfloat16* __restrict__ wv,
    __hip_bfloat16* __restrict__ Q, __hip_bfloat16* __restrict__ K,
    __hip_bfloat16* __restrict__ V)
{
    __shared__ __align__(16) __hip_bfloat16 As[128 * 32];
    __shared__ __align__(16) __hip_bfloat16 Bs[128 * 32];
    const int z = blockIdx.z;
    const __hip_bfloat16* A  = (z == 0) ? hb : hcb;
    const __hip_bfloat16* Bm = (z == 0) ? wq : (z == 1) ? wk : wv;
    __hip_bfloat16* C        = (z == 0) ? Q  : (z == 1) ? K  : V;
    gemm_nt_body32(A, Bm, C, As, Bs, blockIdx.x * 128, blockIdx.y * 128);
}

// ---------------------------------------------------------------------------
// final GEMM, 64x128 tile, 32x32x16 MFMA + swizzle: out[b] = Q[b] @ W2[b]^T
// grid (32, 8, 2) = 512 blocks; wave w: m-tiles {0,32}, n-cols [w*32, w*32+32)
// ---------------------------------------------------------------------------
__global__ __launch_bounds__(256) void gemm_final(
    const __hip_bfloat16* __restrict__ Qg, const __hip_bfloat16* __restrict__ W2g,
    float* __restrict__ outg)
{
    __shared__ __align__(16) __hip_bfloat16 As[64 * 32];    // 4 KB
    __shared__ __align__(16) __hip_bfloat16 Bs[128 * 32];   // 8 KB

    const int b = blockIdx.z;
    const __hip_bfloat16* A  = Qg  + (size_t)b * MM * HH;
    const __hip_bfloat16* Bm = W2g + (size_t)b * HH * HH;
    float* C                 = outg + (size_t)b * MM * HH;
    const int m0 = blockIdx.x * 64;
    const int n0 = blockIdx.y * 128;

    const int t    = threadIdx.x;
    const int lane = t & 63;
    const int wave = t >> 6;
    const int lr = lane >> 2;
    const int lc = (((lane & 3) ^ ((lane >> 3) & 3)) * 8);
    const int fm = lane & 31;
    const int swr = (lane >> 1) & 3;
    const int ghi = lane >> 5;

    f32x16 acc[2] = {};

    for (int k0 = 0; k0 < HH; k0 += 32) {
        __syncthreads();
        async_copy16(A  + (size_t)(m0 + wave * 16 + lr) * HH + (k0 + lc),
                     As + wave * 512);
        async_copy16(Bm + (size_t)(n0 + (2 * wave) * 16 + lr) * HH + (k0 + lc),
                     Bs + (2 * wave) * 512);
        async_copy16(Bm + (size_t)(n0 + (2 * wave + 1) * 16 + lr) * HH + (k0 + lc),
                     Bs + (2 * wave + 1) * 512);
        __syncthreads();

#pragma unroll
        for (int ks = 0; ks < 32; ks += 16) {
            const int pos = ((((ks >> 3) + ghi) ^ swr) * 8);
            s16x8 af[2], bf;
#pragma unroll
            for (int mi = 0; mi < 2; ++mi)
                af[mi] = *(const s16x8*)(As + (mi * 32 + fm) * 32 + pos);
            bf = *(const s16x8*)(Bs + (wave * 32 + fm) * 32 + pos);
#pragma unroll
            for (int mi = 0; mi < 2; ++mi)
                acc[mi] = __builtin_amdgcn_mfma_f32_32x32x16_bf16(
                    af[mi], bf, acc[mi], 0, 0, 0);
        }
    }

    const int ec = lane & 31;
    const int eb = (lane >> 5) * 4;
#pragma unroll
    for (int mi = 0; mi < 2; ++mi)
#pragma unroll
        for (int r = 0; r < 16; ++r) {
            const int m = m0 + mi * 32 + (r & 3) + 8 * (r >> 2) + eb;
            const int n = n0 + wave * 32 + ec;
            C[(size_t)m * HH + n] = acc[mi][r];
        }
}

// ---------------------------------------------------------------------------
// T[b,h,d1,d2] += sum_l K[b,l,h*64+d1] * V[b,l,h*64+d2]  via 16x16x32 MFMA.
// grid (16, KH, BB) = 512 blocks.
// ---------------------------------------------------------------------------
#define CH 128   // l-rows per block
#define LP 136   // padded LDS leading dim (elements)

__global__ __launch_bounds__(256) void kv_outer_mfma(
    const __hip_bfloat16* __restrict__ Km,
    const __hip_bfloat16* __restrict__ Vm,
    float* __restrict__ S)
{
    __shared__ __align__(16) __hip_bfloat16 Kt[64 * LP];  // [d1][l]
    __shared__ __align__(16) __hip_bfloat16 Vt[64 * LP];  // [d2][l]

    const int t = threadIdx.x, head = blockIdx.y, b = blockIdx.z;
    const int l0 = blockIdx.x * CH;

    const int r  = t & 127;
    const int cb = (t >> 7) * 8;
    const size_t gbase = (size_t)(b * MM + l0 + r) * HH + head * 64;
#pragma unroll
    for (int u = 0; u < 4; ++u) {
        const int c8 = cb + u * 16;
        const s16x8 kv = *(const s16x8*)(Km + gbase + c8);
        const s16x8 vv = *(const s16x8*)(Vm + gbase + c8);
#pragma unroll
        for (int j = 0; j < 8; ++j) {
            Kt[(c8 + j) * LP + r] = ((const __hip_bfloat16*)&kv)[j];
            Vt[(c8 + j) * LP + r] = ((const __hip_bfloat16*)&vv)[j];
        }
    }
    __syncthreads();

    const int wave = t >> 6, lane = t & 63;
    const int fr = lane & 15;
    const int fq = (lane >> 4) * 8;
    const int wm = wave * 16;

    f32x4 acc[4] = {};
    for (int kk = 0; kk < CH; kk += 32) {
        const s16x8 af = *(const s16x8*)(Kt + (wm + fr) * LP + kk + fq);
        s16x8 bf[4];
#pragma unroll
        for (int nj = 0; nj < 4; ++nj)
            bf[nj] = *(const s16x8*)(Vt + (nj * 16 + fr) * LP + kk + fq);
#pragma unroll
        for (int nj = 0; nj < 4; ++nj)
            acc[nj] = __builtin_amdgcn_mfma_f32_16x16x32_bf16(af, bf[nj], acc[nj], 0, 0, 0);
    }

    float* Sg = S + ((size_t)b * KH + head) * 4096;
    const int er = (lane >> 4) * 4;
    const int ec = lane & 15;
#pragma unroll
    for (int nj = 0; nj < 4; ++nj)
#pragma unroll
        for (int rr = 0; rr < 4; ++rr)
            atomicAdd(&Sg[(wm + er + rr) * 64 + nj * 16 + ec], acc[nj][rr]);
}

// ---------------------------------------------------------------------------
// W2[b][n][h*64+dp] = sum_d Wo[n][h*64+d] * T[b,h,dp,d]   (bf16 out)
// grid (8, KH, BB), block 256
// ---------------------------------------------------------------------------
__global__ __launch_bounds__(256) void w2_fold(
    const __hip_bfloat16* __restrict__ Wo,
    const float* __restrict__ S,
    __hip_bfloat16* __restrict__ W2)
{
    __shared__ float Sl[64 * 68];
    __shared__ float Wl[128 * 68];
    const int t = threadIdx.x, head = blockIdx.y, b = blockIdx.z;
    const int n0 = blockIdx.x * 128;

    const float* Sg = S + ((size_t)b * KH + head) * 4096;
    for (int idx = t; idx < 4096; idx += 256) {
        const int dp = idx >> 6, d = idx & 63;
        Sl[d * 68 + dp] = Sg[idx];
    }
    for (int idx = t; idx < 1024; idx += 256) {
        const int r = idx >> 3, c8 = (idx & 7) * 8;
        s16x8 wv = *(const s16x8*)(Wo + (size_t)(n0 + r) * HH + head * 64 + c8);
#pragma unroll
        for (int j = 0; j < 8; ++j) {
            __hip_bfloat16 wb = *(((const __hip_bfloat16*)&wv) + j);
            Wl[r * 68 + c8 + j] = __bfloat162float(wb);
        }
    }
    __syncthreads();

    const int dpb = (t & 15) * 4;
    const int ng  = t >> 4;
    float acc[8][4] = {};
    for (int d0 = 0; d0 < 64; d0 += 4) {
        f32x4 sv[4];
#pragma unroll
        for (int r = 0; r < 4; ++r)
            sv[r] = *(const f32x4*)(Sl + (d0 + r) * 68 + dpb);
#pragma unroll
        for (int i = 0; i < 8; ++i) {
            const f32x4 wv = *(const f32x4*)(Wl + (ng + 16 * i) * 68 + d0);
#pragma unroll
            for (int r = 0; r < 4; ++r)
#pragma unroll
                for (int j = 0; j < 4; ++j)
                    acc[i][j] += wv[r] * sv[r][j];
        }
    }

#pragma unroll
    for (int i = 0; i < 8; ++i) {
        bf16x4_t o;
        o.x = __float2bfloat16(acc[i][0]);
        o.y = __float2bfloat16(acc[i][1]);
        o.z = __float2bfloat16(acc[i][2]);
        o.w = __float2bfloat16(acc[i][3]);
        *(bf16x4_t*)(W2 + (size_t)b * HH * HH + (size_t)(n0 + ng + 16 * i) * HH
                     + head * 64 + dpb) = o;
    }
}

// ---------------------------------------------------------------------------
extern "C" void kernel_launch(void* const* d_in, const int* in_sizes, int n_in,
                              void* d_out, int out_size, void* d_ws, size_t ws_size,
                              hipStream_t stream) {
    const float* h_f  = (const float*)d_in[0];
    const float* hc_f = (const float*)d_in[1];
    // d_in[2] = key_pe: DEAD (softmax result unused by reference output)
    const float* Wq_f = (const float*)d_in[3];
    const float* Wk_f = (const float*)d_in[4];
    const float* Wv_f = (const float*)d_in[5];
    const float* Wo_f = (const float*)d_in[6];
    float* out = (float*)d_out;

    const size_t act_b = (size_t)BB * MM * HH * 2;  // 8 MB
    const size_t w_b   = (size_t)HH * HH * 2;       // 2 MB
    char* ws = (char*)d_ws;
    __hip_bfloat16* hb   = (__hip_bfloat16*)(ws);
    __hip_bfloat16* hcb  = (__hip_bfloat16*)(ws + act_b);
    __hip_bfloat16* wqb  = (__hip_bfloat16*)(ws + 2 * act_b);
    __hip_bfloat16* wkb  = (__hip_bfloat16*)(ws + 2 * act_b + w_b);
    __hip_bfloat16* wvb  = (__hip_bfloat16*)(ws + 2 * act_b + 2 * w_b);
    __hip_bfloat16* wob  = (__hip_bfloat16*)(ws + 2 * act_b + 3 * w_b);
    __hip_bfloat16* Qbuf = (__hip_bfloat16*)(ws + 2 * act_b + 4 * w_b);
    __hip_bfloat16* Kbuf = (__hip_bfloat16*)(ws + 3 * act_b + 4 * w_b);
    __hip_bfloat16* Vbuf = (__hip_bfloat16*)(ws + 4 * act_b + 4 * w_b);
    float*          Sbuf = (float*)(ws + 5 * act_b + 4 * w_b);            // 512 KB
    __hip_bfloat16* W2   = (__hip_bfloat16*)(ws + 5 * act_b + 4 * w_b + (size_t)512 * 1024);

    const dim3 blk(256);

    // 0: fp32->bf16 converts + Sbuf zeroing in one dispatch
    cvt7<<<dim3(4096, 7), blk, 0, stream>>>(h_f, hc_f, Wq_f, Wk_f, Wv_f, Wo_f,
                                            hb, hcb, wqb, wkb, wvb, wob, Sbuf);

    // 1: fused Q/K/V projections (32x32x16 MFMA, swizzled LDS)
    gemm_qkv<<<dim3(32, 8, 3), blk, 0, stream>>>(hb, hcb, wqb, wkb, wvb,
                                                 Qbuf, Kbuf, Vbuf);

    // 2: T = K^T V per head (MFMA, atomic partials into zeroed Sbuf)
    kv_outer_mfma<<<dim3(MM / CH, KH, BB), blk, 0, stream>>>(Kbuf, Vbuf, Sbuf);

    // 3: W2 = blockdiag(T) folded into Wo
    w2_fold<<<dim3(8, KH, BB), blk, 0, stream>>>(wob, Sbuf, W2);

    // 4: final = Q @ W2^T (fp32 out, 512 blocks, 32x32x16 MFMA, swizzled)
    gemm_final<<<dim3(32, 8, 2), blk, 0, stream>>>(Qbuf, W2, out);
}

// Round 7
// 174.097 us; speedup vs baseline: 1.0257x; 1.0006x over previous
//
#include <hip/hip_runtime.h>
#include <hip/hip_bf16.h>

// Problem dims (fixed): B=2, M=L=2048, H=1024, K_HEADS=16, D=64
// All inputs/output are FLOAT32; compute in bf16 MFMA with f32 accumulation.
// Algebra: softmax branch is dead; out = Q (K^T V) blockdiag Wo^T, folded as
//   T = K^T V (per head, 64x64)
//   W2[n][h*64+dp] = sum_d Wo[n][h*64+d] T[h][dp][d]
//   F  = W2 @ Wq          (per batch, 1024x1024)   <- replaces Q projection
//   out_b = h_b @ F_b^T
// Big GEMMs: 32x32x16 bf16 MFMA, BK=64 (half the barriers of BK=32), 8-group
// XOR-swizzled LDS (row stride 128 B starts every row at bank 0 unswizzled).
#define BB 2
#define MM 2048
#define HH 1024
#define KH 16

typedef short s16x8 __attribute__((ext_vector_type(8)));
typedef float f32x4 __attribute__((ext_vector_type(4)));
typedef float f32x16 __attribute__((ext_vector_type(16)));

#define GLOBAL_AS __attribute__((address_space(1)))
#define LDS_AS    __attribute__((address_space(3)))

__device__ __forceinline__ void async_copy16(const void* g, void* l) {
    __builtin_amdgcn_global_load_lds((const GLOBAL_AS void*)g, (LDS_AS void*)l, 16, 0, 0);
}

struct __align__(8) bf16x4_t { __hip_bfloat16 x, y, z, w; };

// ---------------------------------------------------------------------------
// fused fp32 -> bf16 conversion + Sbuf zeroing: grid (4096, 6)
// segs: 0=h, 1=h_cache, 2=Wk, 3=Wv, 4=Wo, 5=zero Sbuf
// ---------------------------------------------------------------------------
__global__ __launch_bounds__(256) void cvt6b(
    const float* __restrict__ s0, const float* __restrict__ s1,
    const float* __restrict__ s2, const float* __restrict__ s3,
    const float* __restrict__ s4,
    __hip_bfloat16* __restrict__ d0, __hip_bfloat16* __restrict__ d1,
    __hip_bfloat16* __restrict__ d2, __hip_bfloat16* __restrict__ d3,
    __hip_bfloat16* __restrict__ d4,
    float* __restrict__ Sz)
{
    const int seg = blockIdx.y;
    const int i = (blockIdx.x * 256 + threadIdx.x) * 4;
    if (seg == 5) {
        if (i + 3 < BB * KH * 64 * 64) {
            float4 z = {0.f, 0.f, 0.f, 0.f};
            *(float4*)(Sz + i) = z;
        }
        return;
    }
    const float* src;
    __hip_bfloat16* dst;
    int n;
    switch (seg) {
        case 0: src = s0; dst = d0; n = BB * MM * HH; break;
        case 1: src = s1; dst = d1; n = BB * MM * HH; break;
        case 2: src = s2; dst = d2; n = HH * HH; break;
        case 3: src = s3; dst = d3; n = HH * HH; break;
        default: src = s4; dst = d4; n = HH * HH; break;
    }
    if (i + 3 < n) {
        const float4 v = *(const float4*)(src + i);
        bf16x4_t o;
        o.x = __float2bfloat16(v.x);
        o.y = __float2bfloat16(v.y);
        o.z = __float2bfloat16(v.z);
        o.w = __float2bfloat16(v.w);
        *(bf16x4_t*)(dst + i) = o;
    }
}

// ---------------------------------------------------------------------------
// Wq f32 [j][k] -> WqT bf16 [k][j]  (LDS 64x65-tiled transpose + convert)
// grid (16,16), block 256
// ---------------------------------------------------------------------------
__global__ __launch_bounds__(256) void transpose_wq(
    const float* __restrict__ Wq, __hip_bfloat16* __restrict__ WqT)
{
    __shared__ float Tl[64][65];
    const int j0 = blockIdx.x * 64;   // Wq row block
    const int k0 = blockIdx.y * 64;   // Wq col block
    const int t = threadIdx.x;
    const int r = t >> 6;   // 0..3
    const int c = t & 63;
#pragma unroll
    for (int i = 0; i < 64; i += 4)
        Tl[r + i][c] = Wq[(size_t)(j0 + r + i) * HH + k0 + c];
    __syncthreads();
#pragma unroll
    for (int i = 0; i < 64; i += 4)
        WqT[(size_t)(k0 + r + i) * HH + j0 + c] = __float2bfloat16(Tl[c][r + i]);
}

// ---------------------------------------------------------------------------
// BK=64 NT GEMM bodies. LDS row stride 64 elems (128 B). Swizzle: LDS(row,pos)
// holds global k-group pos ^ (row&7); staging lane (slot pos=lane&7, row
// lane>>3 within 8-row issue) fetches group (lane&7)^((lane>>3)&7) — exact
// because all chunk row bases are multiples of 8. Frag read for logical group
// g at row fm: pos = g ^ (fm&7). 8 lanes per 4-bank span -> b128 8-cycle floor.
// C/D: col = lane&31, row = (reg&3) + 8*(reg>>2) + 4*(lane>>5)  [m74/m101]
// ---------------------------------------------------------------------------
__device__ __forceinline__ void store_c(__hip_bfloat16* C, size_t idx, float v) {
    C[idx] = __float2bfloat16(v);
}
__device__ __forceinline__ void store_c(float* C, size_t idx, float v) { C[idx] = v; }

// 128x128 tile
template <typename OutT>
__device__ __forceinline__ void gemm_nt_body64(
    const __hip_bfloat16* __restrict__ A,
    const __hip_bfloat16* __restrict__ Bm,
    OutT* __restrict__ C,
    __hip_bfloat16* As, __hip_bfloat16* Bs,
    int m0, int n0)
{
    const int t    = threadIdx.x;
    const int lane = t & 63;
    const int wave = t >> 6;

    const int srow = lane >> 3;                      // staging row 0..7
    const int sw   = ((lane & 7) ^ srow) * 8;        // swizzled col group

    const int wm  = (wave >> 1) * 64;
    const int wn  = (wave & 1) * 64;
    const int fm  = lane & 31;
    const int fm7 = fm & 7;
    const int ghi = lane >> 5;

    f32x16 acc[2][2] = {};

    for (int k0 = 0; k0 < HH; k0 += 64) {
        __syncthreads();
#pragma unroll
        for (int i = 0; i < 2; ++i) {
            const int c = wave * 2 + i;
            const __hip_bfloat16* ag = A + (size_t)(m0 + c * 16 + srow) * HH + k0 + sw;
            async_copy16(ag,          As + c * 1024);
            async_copy16(ag + 8 * HH, As + c * 1024 + 512);
            const __hip_bfloat16* bg = Bm + (size_t)(n0 + c * 16 + srow) * HH + k0 + sw;
            async_copy16(bg,          Bs + c * 1024);
            async_copy16(bg + 8 * HH, Bs + c * 1024 + 512);
        }
        __syncthreads();

#pragma unroll
        for (int ks = 0; ks < 64; ks += 16) {
            const int pos = ((((ks >> 3) + ghi) ^ fm7) * 8);
            s16x8 af[2], bf[2];
#pragma unroll
            for (int mi = 0; mi < 2; ++mi)
                af[mi] = *(const s16x8*)(As + (wm + mi * 32 + fm) * 64 + pos);
#pragma unroll
            for (int ni = 0; ni < 2; ++ni)
                bf[ni] = *(const s16x8*)(Bs + (wn + ni * 32 + fm) * 64 + pos);
#pragma unroll
            for (int mi = 0; mi < 2; ++mi)
#pragma unroll
                for (int ni = 0; ni < 2; ++ni)
                    acc[mi][ni] = __builtin_amdgcn_mfma_f32_32x32x16_bf16(
                        af[mi], bf[ni], acc[mi][ni], 0, 0, 0);
        }
    }

    const int ec = lane & 31;
    const int eb = (lane >> 5) * 4;
#pragma unroll
    for (int mi = 0; mi < 2; ++mi)
#pragma unroll
        for (int ni = 0; ni < 2; ++ni)
#pragma unroll
            for (int r = 0; r < 16; ++r) {
                const int m = m0 + wm + mi * 32 + (r & 3) + 8 * (r >> 2) + eb;
                const int n = n0 + wn + ni * 32 + ec;
                store_c(C, (size_t)m * HH + n, acc[mi][ni][r]);
            }
}

// 64x128 tile (wave w: both 32-m-tiles, n-cols [w*32, w*32+32))
template <typename OutT>
__device__ __forceinline__ void gemm_nt_body64_m64(
    const __hip_bfloat16* __restrict__ A,
    const __hip_bfloat16* __restrict__ Bm,
    OutT* __restrict__ C,
    __hip_bfloat16* As, __hip_bfloat16* Bs,
    int m0, int n0)
{
    const int t    = threadIdx.x;
    const int lane = t & 63;
    const int wave = t >> 6;

    const int srow = lane >> 3;
    const int sw   = ((lane & 7) ^ srow) * 8;

    const int wn  = wave * 32;
    const int fm  = lane & 31;
    const int fm7 = fm & 7;
    const int ghi = lane >> 5;

    f32x16 acc[2] = {};

    for (int k0 = 0; k0 < HH; k0 += 64) {
        __syncthreads();
        {
            const __hip_bfloat16* ag = A + (size_t)(m0 + wave * 16 + srow) * HH + k0 + sw;
            async_copy16(ag,          As + wave * 1024);
            async_copy16(ag + 8 * HH, As + wave * 1024 + 512);
        }
#pragma unroll
        for (int i = 0; i < 2; ++i) {
            const int c = wave * 2 + i;
            const __hip_bfloat16* bg = Bm + (size_t)(n0 + c * 16 + srow) * HH + k0 + sw;
            async_copy16(bg,          Bs + c * 1024);
            async_copy16(bg + 8 * HH, Bs + c * 1024 + 512);
        }
        __syncthreads();

#pragma unroll
        for (int ks = 0; ks < 64; ks += 16) {
            const int pos = ((((ks >> 3) + ghi) ^ fm7) * 8);
            s16x8 af[2], bf;
#pragma unroll
            for (int mi = 0; mi < 2; ++mi)
                af[mi] = *(const s16x8*)(As + (mi * 32 + fm) * 64 + pos);
            bf = *(const s16x8*)(Bs + (wn + fm) * 64 + pos);
#pragma unroll
            for (int mi = 0; mi < 2; ++mi)
                acc[mi] = __builtin_amdgcn_mfma_f32_32x32x16_bf16(
                    af[mi], bf, acc[mi], 0, 0, 0);
        }
    }

    const int ec = lane & 31;
    const int eb = (lane >> 5) * 4;
#pragma unroll
    for (int mi = 0; mi < 2; ++mi)
#pragma unroll
        for (int r = 0; r < 16; ++r) {
            const int m = m0 + mi * 32 + (r & 3) + 8 * (r >> 2) + eb;
            const int n = n0 + wn + ec;
            store_c(C, (size_t)m * HH + n, acc[mi][r]);
        }
}

// fused K/V projections: grid (32, 8, 2) = 512 blocks
__global__ __launch_bounds__(256) void gemm_kv(
    const __hip_bfloat16* __restrict__ hcb,
    const __hip_bfloat16* __restrict__ wk, const __hip_bfloat16* __restrict__ wv,
    __hip_bfloat16* __restrict__ K, __hip_bfloat16* __restrict__ V)
{
    __shared__ __align__(16) __hip_bfloat16 As[128 * 64];  // 16 KB
    __shared__ __align__(16) __hip_bfloat16 Bs[128 * 64];  // 16 KB
    const int z = blockIdx.z;
    gemm_nt_body64(hcb, z ? wv : wk, z ? V : K, As, Bs,
                   blockIdx.x * 128, blockIdx.y * 128);
}

// F_b = W2_b @ WqT^T (= W2_b @ Wq), bf16 out: grid (16, 8, 2) = 256 blocks
__global__ __launch_bounds__(256) void gemm_f(
    const __hip_bfloat16* __restrict__ W2, const __hip_bfloat16* __restrict__ WqT,
    __hip_bfloat16* __restrict__ F)
{
    __shared__ __align__(16) __hip_bfloat16 As[64 * 64];    // 8 KB
    __shared__ __align__(16) __hip_bfloat16 Bs[128 * 64];   // 16 KB
    const int b = blockIdx.z;
    gemm_nt_body64_m64(W2 + (size_t)b * HH * HH, WqT, F + (size_t)b * HH * HH,
                       As, Bs, blockIdx.x * 64, blockIdx.y * 128);
}

// out_b = h_b @ F_b^T, fp32 out: grid (32, 8, 2) = 512 blocks
__global__ __launch_bounds__(256) void gemm_final(
    const __hip_bfloat16* __restrict__ hb, const __hip_bfloat16* __restrict__ F,
    float* __restrict__ outg)
{
    __shared__ __align__(16) __hip_bfloat16 As[64 * 64];    // 8 KB
    __shared__ __align__(16) __hip_bfloat16 Bs[128 * 64];   // 16 KB
    const int b = blockIdx.z;
    gemm_nt_body64_m64(hb + (size_t)b * MM * HH, F + (size_t)b * HH * HH,
                       outg + (size_t)b * MM * HH, As, Bs,
                       blockIdx.x * 64, blockIdx.y * 128);
}

// ---------------------------------------------------------------------------
// T[b,h,d1,d2] += sum_l K[b,l,h*64+d1] * V[b,l,h*64+d2]  via 16x16x32 MFMA.
// grid (16, KH, BB) = 512 blocks.  (verified round 3-6)
// ---------------------------------------------------------------------------
#define CH 128
#define LP 136

__global__ __launch_bounds__(256) void kv_outer_mfma(
    const __hip_bfloat16* __restrict__ Km,
    const __hip_bfloat16* __restrict__ Vm,
    float* __restrict__ S)
{
    __shared__ __align__(16) __hip_bfloat16 Kt[64 * LP];
    __shared__ __align__(16) __hip_bfloat16 Vt[64 * LP];

    const int t = threadIdx.x, head = blockIdx.y, b = blockIdx.z;
    const int l0 = blockIdx.x * CH;

    const int r  = t & 127;
    const int cb = (t >> 7) * 8;
    const size_t gbase = (size_t)(b * MM + l0 + r) * HH + head * 64;
#pragma unroll
    for (int u = 0; u < 4; ++u) {
        const int c8 = cb + u * 16;
        const s16x8 kv = *(const s16x8*)(Km + gbase + c8);
        const s16x8 vv = *(const s16x8*)(Vm + gbase + c8);
#pragma unroll
        for (int j = 0; j < 8; ++j) {
            Kt[(c8 + j) * LP + r] = ((const __hip_bfloat16*)&kv)[j];
            Vt[(c8 + j) * LP + r] = ((const __hip_bfloat16*)&vv)[j];
        }
    }
    __syncthreads();

    const int wave = t >> 6, lane = t & 63;
    const int fr = lane & 15;
    const int fq = (lane >> 4) * 8;
    const int wm = wave * 16;

    f32x4 acc[4] = {};
    for (int kk = 0; kk < CH; kk += 32) {
        const s16x8 af = *(const s16x8*)(Kt + (wm + fr) * LP + kk + fq);
        s16x8 bf[4];
#pragma unroll
        for (int nj = 0; nj < 4; ++nj)
            bf[nj] = *(const s16x8*)(Vt + (nj * 16 + fr) * LP + kk + fq);
#pragma unroll
        for (int nj = 0; nj < 4; ++nj)
            acc[nj] = __builtin_amdgcn_mfma_f32_16x16x32_bf16(af, bf[nj], acc[nj], 0, 0, 0);
    }

    float* Sg = S + ((size_t)b * KH + head) * 4096;
    const int er = (lane >> 4) * 4;
    const int ec = lane & 15;
#pragma unroll
    for (int nj = 0; nj < 4; ++nj)
#pragma unroll
        for (int rr = 0; rr < 4; ++rr)
            atomicAdd(&Sg[(wm + er + rr) * 64 + nj * 16 + ec], acc[nj][rr]);
}

// ---------------------------------------------------------------------------
// W2[b][n][h*64+dp] = sum_d Wo[n][h*64+d] * T[b,h,dp,d]   (bf16 out)
// grid (8, KH, BB), block 256  (verified round 2-6)
// ---------------------------------------------------------------------------
__global__ __launch_bounds__(256) void w2_fold(
    const __hip_bfloat16* __restrict__ Wo,
    const float* __restrict__ S,
    __hip_bfloat16* __restrict__ W2)
{
    __shared__ float Sl[64 * 68];
    __shared__ float Wl[128 * 68];
    const int t = threadIdx.x, head = blockIdx.y, b = blockIdx.z;
    const int n0 = blockIdx.x * 128;

    const float* Sg = S + ((size_t)b * KH + head) * 4096;
    for (int idx = t; idx < 4096; idx += 256) {
        const int dp = idx >> 6, d = idx & 63;
        Sl[d * 68 + dp] = Sg[idx];
    }
    for (int idx = t; idx < 1024; idx += 256) {
        const int r = idx >> 3, c8 = (idx & 7) * 8;
        s16x8 wv = *(const s16x8*)(Wo + (size_t)(n0 + r) * HH + head * 64 + c8);
#pragma unroll
        for (int j = 0; j < 8; ++j) {
            __hip_bfloat16 wb = *(((const __hip_bfloat16*)&wv) + j);
            Wl[r * 68 + c8 + j] = __bfloat162float(wb);
        }
    }
    __syncthreads();

    const int dpb = (t & 15) * 4;
    const int ng  = t >> 4;
    float acc[8][4] = {};
    for (int d0 = 0; d0 < 64; d0 += 4) {
        f32x4 sv[4];
#pragma unroll
        for (int r = 0; r < 4; ++r)
            sv[r] = *(const f32x4*)(Sl + (d0 + r) * 68 + dpb);
#pragma unroll
        for (int i = 0; i < 8; ++i) {
            const f32x4 wv = *(const f32x4*)(Wl + (ng + 16 * i) * 68 + d0);
#pragma unroll
            for (int r = 0; r < 4; ++r)
#pragma unroll
                for (int j = 0; j < 4; ++j)
                    acc[i][j] += wv[r] * sv[r][j];
        }
    }

#pragma unroll
    for (int i = 0; i < 8; ++i) {
        bf16x4_t o;
        o.x = __float2bfloat16(acc[i][0]);
        o.y = __float2bfloat16(acc[i][1]);
        o.z = __float2bfloat16(acc[i][2]);
        o.w = __float2bfloat16(acc[i][3]);
        *(bf16x4_t*)(W2 + (size_t)b * HH * HH + (size_t)(n0 + ng + 16 * i) * HH
                     + head * 64 + dpb) = o;
    }
}

// ---------------------------------------------------------------------------
extern "C" void kernel_launch(void* const* d_in, const int* in_sizes, int n_in,
                              void* d_out, int out_size, void* d_ws, size_t ws_size,
                              hipStream_t stream) {
    const float* h_f  = (const float*)d_in[0];
    const float* hc_f = (const float*)d_in[1];
    // d_in[2] = key_pe: DEAD (softmax result unused by reference output)
    const float* Wq_f = (const float*)d_in[3];
    const float* Wk_f = (const float*)d_in[4];
    const float* Wv_f = (const float*)d_in[5];
    const float* Wo_f = (const float*)d_in[6];
    float* out = (float*)d_out;

    const size_t act_b = (size_t)BB * MM * HH * 2;  // 8 MB
    const size_t w_b   = (size_t)HH * HH * 2;       // 2 MB
    char* ws = (char*)d_ws;
    __hip_bfloat16* hb   = (__hip_bfloat16*)(ws);                       // 8 MB
    __hip_bfloat16* hcb  = (__hip_bfloat16*)(ws + act_b);               // 8 MB
    __hip_bfloat16* wkb  = (__hip_bfloat16*)(ws + 2 * act_b);           // 2 MB
    __hip_bfloat16* wvb  = (__hip_bfloat16*)(ws + 2 * act_b + w_b);     // 2 MB
    __hip_bfloat16* wob  = (__hip_bfloat16*)(ws + 2 * act_b + 2 * w_b); // 2 MB
    __hip_bfloat16* wqt  = (__hip_bfloat16*)(ws + 2 * act_b + 3 * w_b); // 2 MB
    __hip_bfloat16* Kbuf = (__hip_bfloat16*)(ws + 2 * act_b + 4 * w_b); // 8 MB
    __hip_bfloat16* Vbuf = (__hip_bfloat16*)(ws + 3 * act_b + 4 * w_b); // 8 MB
    float*          Sbuf = (float*)(ws + 4 * act_b + 4 * w_b);          // 512 KB
    __hip_bfloat16* W2   = (__hip_bfloat16*)(ws + 4 * act_b + 4 * w_b + (size_t)512 * 1024);  // 4 MB
    __hip_bfloat16* Fbuf = (__hip_bfloat16*)(ws + 4 * act_b + 6 * w_b + (size_t)512 * 1024);  // 4 MB

    const dim3 blk(256);

    // 0: fp32->bf16 converts + Sbuf zeroing; Wq transpose-convert
    cvt6b<<<dim3(4096, 6), blk, 0, stream>>>(h_f, hc_f, Wk_f, Wv_f, Wo_f,
                                             hb, hcb, wkb, wvb, wob, Sbuf);
    transpose_wq<<<dim3(16, 16), blk, 0, stream>>>(Wq_f, wqt);

    // 1: K/V projections (BK=64, swizzled)
    gemm_kv<<<dim3(32, 8, 2), blk, 0, stream>>>(hcb, wkb, wvb, Kbuf, Vbuf);

    // 2: T = K^T V per head (MFMA, atomic partials into zeroed Sbuf)
    kv_outer_mfma<<<dim3(MM / CH, KH, BB), blk, 0, stream>>>(Kbuf, Vbuf, Sbuf);

    // 3: W2 = blockdiag(T) folded into Wo
    w2_fold<<<dim3(8, KH, BB), blk, 0, stream>>>(wob, Sbuf, W2);

    // 4: F = W2 @ Wq (replaces the Q projection: out = h (W2 Wq)^T)
    gemm_f<<<dim3(16, 8, 2), blk, 0, stream>>>(W2, wqt, Fbuf);

    // 5: out = h @ F^T (fp32 out)
    gemm_final<<<dim3(32, 8, 2), blk, 0, stream>>>(hb, Fbuf, out);
}

// Round 8
// 166.716 us; speedup vs baseline: 1.0712x; 1.0443x over previous
//
#include <hip/hip_runtime.h>
#include <hip/hip_bf16.h>

// Problem dims (fixed): B=2, M=L=2048, H=1024, K_HEADS=16, D=64
// All inputs/output are FLOAT32; compute in bf16 MFMA with f32 accumulation.
// Algebra: softmax branch is dead; out = Q (K^T V) blockdiag Wo^T, folded as
//   T_h = K_h^T V_h (per head, 64x64)          [fused into the K/V projection]
//   W2[n][h*64+dp] = sum_d Wo[n][h*64+d] T[h][dp][d]
//   F_b = W2_b @ Wq                            (replaces the Q projection)
//   out_b = h_b @ F_b^T
// Big GEMMs: 32x32x16 bf16 MFMA, BK=64, 8-group XOR-swizzled LDS.
#define BB 2
#define MM 2048
#define HH 1024
#define KH 16

typedef short s16x8 __attribute__((ext_vector_type(8)));
typedef float f32x4 __attribute__((ext_vector_type(4)));
typedef float f32x16 __attribute__((ext_vector_type(16)));

#define GLOBAL_AS __attribute__((address_space(1)))
#define LDS_AS    __attribute__((address_space(3)))

__device__ __forceinline__ void async_copy16(const void* g, void* l) {
    __builtin_amdgcn_global_load_lds((const GLOBAL_AS void*)g, (LDS_AS void*)l, 16, 0, 0);
}

struct __align__(8) bf16x4_t { __hip_bfloat16 x, y, z, w; };

// ---------------------------------------------------------------------------
// fused fp32 -> bf16 conversion + Sbuf zeroing: grid (4096, 6)
// segs: 0=h, 1=h_cache, 2=Wk, 3=Wv, 4=Wo, 5=zero Sbuf
// ---------------------------------------------------------------------------
__global__ __launch_bounds__(256) void cvt6b(
    const float* __restrict__ s0, const float* __restrict__ s1,
    const float* __restrict__ s2, const float* __restrict__ s3,
    const float* __restrict__ s4,
    __hip_bfloat16* __restrict__ d0, __hip_bfloat16* __restrict__ d1,
    __hip_bfloat16* __restrict__ d2, __hip_bfloat16* __restrict__ d3,
    __hip_bfloat16* __restrict__ d4,
    float* __restrict__ Sz)
{
    const int seg = blockIdx.y;
    const int i = (blockIdx.x * 256 + threadIdx.x) * 4;
    if (seg == 5) {
        if (i + 3 < BB * KH * 64 * 64) {
            float4 z = {0.f, 0.f, 0.f, 0.f};
            *(float4*)(Sz + i) = z;
        }
        return;
    }
    const float* src;
    __hip_bfloat16* dst;
    int n;
    switch (seg) {
        case 0: src = s0; dst = d0; n = BB * MM * HH; break;
        case 1: src = s1; dst = d1; n = BB * MM * HH; break;
        case 2: src = s2; dst = d2; n = HH * HH; break;
        case 3: src = s3; dst = d3; n = HH * HH; break;
        default: src = s4; dst = d4; n = HH * HH; break;
    }
    if (i + 3 < n) {
        const float4 v = *(const float4*)(src + i);
        bf16x4_t o;
        o.x = __float2bfloat16(v.x);
        o.y = __float2bfloat16(v.y);
        o.z = __float2bfloat16(v.z);
        o.w = __float2bfloat16(v.w);
        *(bf16x4_t*)(dst + i) = o;
    }
}

// ---------------------------------------------------------------------------
// Wq f32 [j][k] -> WqT bf16 [k][j]  (LDS 64x65-tiled transpose + convert)
// grid (16,16), block 256
// ---------------------------------------------------------------------------
__global__ __launch_bounds__(256) void transpose_wq(
    const float* __restrict__ Wq, __hip_bfloat16* __restrict__ WqT)
{
    __shared__ float Tl[64][65];
    const int j0 = blockIdx.x * 64;
    const int k0 = blockIdx.y * 64;
    const int t = threadIdx.x;
    const int r = t >> 6;
    const int c = t & 63;
#pragma unroll
    for (int i = 0; i < 64; i += 4)
        Tl[r + i][c] = Wq[(size_t)(j0 + r + i) * HH + k0 + c];
    __syncthreads();
#pragma unroll
    for (int i = 0; i < 64; i += 4)
        WqT[(size_t)(k0 + r + i) * HH + j0 + c] = __float2bfloat16(Tl[c][r + i]);
}

// ---------------------------------------------------------------------------
// store helpers
// ---------------------------------------------------------------------------
__device__ __forceinline__ void store_c(__hip_bfloat16* C, size_t idx, float v) {
    C[idx] = __float2bfloat16(v);
}
__device__ __forceinline__ void store_c(float* C, size_t idx, float v) { C[idx] = v; }

// ---------------------------------------------------------------------------
// FUSED K/V projection + T = K^T V   (grid (32 l-tiles, 16 heads) = 512 blks)
// Phase 1: K-tile[128x64] = hcb_tile @ Wk_h^T, V-tile likewise — A staged once,
//          BK=64, XOR-swizzled LDS, 32x32x16 MFMA, K/V stay in registers.
// Phase 2: acc -> bf16 -> LDS [d][l] (stride 136, same layout as the verified
//          kv_outer_mfma), then T-MFMA (16x16x32) + atomicAdd into S.
// ---------------------------------------------------------------------------
#define LP2 136

__global__ __launch_bounds__(256) void gemm_kvt(
    const __hip_bfloat16* __restrict__ hcb,
    const __hip_bfloat16* __restrict__ wk, const __hip_bfloat16* __restrict__ wv,
    float* __restrict__ S)
{
    __shared__ __align__(16) char smem[64 * LP2 * 2 * 2];  // 34816 B
    __hip_bfloat16* As  = (__hip_bfloat16*)smem;            // 16 KB (128x64)
    __hip_bfloat16* Bsk = (__hip_bfloat16*)(smem + 16384);  //  8 KB (64x64)
    __hip_bfloat16* Bsv = (__hip_bfloat16*)(smem + 24576);  //  8 KB (64x64)
    __hip_bfloat16* Kt  = (__hip_bfloat16*)smem;            // 17408 B (64xLP2)
    __hip_bfloat16* Vt  = (__hip_bfloat16*)(smem + 64 * LP2 * 2);

    const int t    = threadIdx.x;
    const int lane = t & 63;
    const int wave = t >> 6;
    const int head = blockIdx.y;
    const int m0   = blockIdx.x * 128;       // global row into [B*M, H]
    const int n0   = head * 64;              // weight row offset
    const int b    = blockIdx.x >> 4;        // batch (16 l-tiles per batch)

    const int srow = lane >> 3;                      // staging row 0..7
    const int sw   = ((lane & 7) ^ srow) * 8;        // swizzled col group

    const int wm  = (wave >> 1) * 64;        // wave l-half
    const int wn  = (wave & 1) * 32;         // wave d-half
    const int fm  = lane & 31;
    const int fm7 = fm & 7;
    const int ghi = lane >> 5;

    f32x16 acck[2] = {};
    f32x16 accv[2] = {};

    for (int k0 = 0; k0 < HH; k0 += 64) {
        __syncthreads();
        // A: 16 chunks of 8 rows; wave handles 4
#pragma unroll
        for (int i = 0; i < 4; ++i) {
            const int c = wave * 4 + i;
            async_copy16(hcb + (size_t)(m0 + c * 8 + srow) * HH + k0 + sw,
                         As + c * 512);
        }
        // Bk/Bv: 8 chunks of 8 rows each; wave handles 2 of each
#pragma unroll
        for (int i = 0; i < 2; ++i) {
            const int c = wave * 2 + i;
            async_copy16(wk + (size_t)(n0 + c * 8 + srow) * HH + k0 + sw,
                         Bsk + c * 512);
            async_copy16(wv + (size_t)(n0 + c * 8 + srow) * HH + k0 + sw,
                         Bsv + c * 512);
        }
        __syncthreads();

#pragma unroll
        for (int ks = 0; ks < 64; ks += 16) {
            const int pos = ((((ks >> 3) + ghi) ^ fm7) * 8);
            s16x8 af[2];
#pragma unroll
            for (int mi = 0; mi < 2; ++mi)
                af[mi] = *(const s16x8*)(As + (wm + mi * 32 + fm) * 64 + pos);
            const s16x8 bk = *(const s16x8*)(Bsk + (wn + fm) * 64 + pos);
            const s16x8 bv = *(const s16x8*)(Bsv + (wn + fm) * 64 + pos);
#pragma unroll
            for (int mi = 0; mi < 2; ++mi) {
                acck[mi] = __builtin_amdgcn_mfma_f32_32x32x16_bf16(af[mi], bk, acck[mi], 0, 0, 0);
                accv[mi] = __builtin_amdgcn_mfma_f32_32x32x16_bf16(af[mi], bv, accv[mi], 0, 0, 0);
            }
        }
    }

    // ---- Phase 2: dump K/V tiles to LDS as [d][l] (bf16), then T-MFMA ----
    __syncthreads();   // staging LDS reads done; safe to overwrite with Kt/Vt

    // C/D layout: l = wm + mi*32 + (r&3) + 8*(r>>2) + 4*(lane>>5); d = wn + (lane&31)
    const int dcol = wn + (lane & 31);
    const int lhi  = 4 * (lane >> 5);
#pragma unroll
    for (int mi = 0; mi < 2; ++mi)
#pragma unroll
        for (int g = 0; g < 4; ++g) {
            const int lb = wm + mi * 32 + 8 * g + lhi;   // 4 consecutive l
            bf16x4_t ok, ov;
            ok.x = __float2bfloat16(acck[mi][4 * g + 0]);
            ok.y = __float2bfloat16(acck[mi][4 * g + 1]);
            ok.z = __float2bfloat16(acck[mi][4 * g + 2]);
            ok.w = __float2bfloat16(acck[mi][4 * g + 3]);
            ov.x = __float2bfloat16(accv[mi][4 * g + 0]);
            ov.y = __float2bfloat16(accv[mi][4 * g + 1]);
            ov.z = __float2bfloat16(accv[mi][4 * g + 2]);
            ov.w = __float2bfloat16(accv[mi][4 * g + 3]);
            *(bf16x4_t*)(Kt + dcol * LP2 + lb) = ok;
            *(bf16x4_t*)(Vt + dcol * LP2 + lb) = ov;
        }
    __syncthreads();

    // T-MFMA: A = Kt (d1 x l), B = Vt (d2 x l), 16x16x32, l-reduction = 128
    const int fr = lane & 15;
    const int fq = (lane >> 4) * 8;
    const int wm2 = wave * 16;

    f32x4 acc2[4] = {};
#pragma unroll
    for (int kk = 0; kk < 128; kk += 32) {
        const s16x8 af = *(const s16x8*)(Kt + (wm2 + fr) * LP2 + kk + fq);
        s16x8 bf[4];
#pragma unroll
        for (int nj = 0; nj < 4; ++nj)
            bf[nj] = *(const s16x8*)(Vt + (nj * 16 + fr) * LP2 + kk + fq);
#pragma unroll
        for (int nj = 0; nj < 4; ++nj)
            acc2[nj] = __builtin_amdgcn_mfma_f32_16x16x32_bf16(af, bf[nj], acc2[nj], 0, 0, 0);
    }

    float* Sg = S + ((size_t)b * KH + head) * 4096;
    const int er = (lane >> 4) * 4;
    const int ec = lane & 15;
#pragma unroll
    for (int nj = 0; nj < 4; ++nj)
#pragma unroll
        for (int rr = 0; rr < 4; ++rr)
            atomicAdd(&Sg[(wm2 + er + rr) * 64 + nj * 16 + ec], acc2[nj][rr]);
}

// ---------------------------------------------------------------------------
// 64x128-tile BK=64 NT GEMM body (round-7 verified): wave w: both 32-m-tiles,
// n-cols [w*32, w*32+32)
// ---------------------------------------------------------------------------
template <typename OutT>
__device__ __forceinline__ void gemm_nt_body64_m64(
    const __hip_bfloat16* __restrict__ A,
    const __hip_bfloat16* __restrict__ Bm,
    OutT* __restrict__ C,
    __hip_bfloat16* As, __hip_bfloat16* Bs,
    int m0, int n0)
{
    const int t    = threadIdx.x;
    const int lane = t & 63;
    const int wave = t >> 6;

    const int srow = lane >> 3;
    const int sw   = ((lane & 7) ^ srow) * 8;

    const int wn  = wave * 32;
    const int fm  = lane & 31;
    const int fm7 = fm & 7;
    const int ghi = lane >> 5;

    f32x16 acc[2] = {};

    for (int k0 = 0; k0 < HH; k0 += 64) {
        __syncthreads();
        {
            const __hip_bfloat16* ag = A + (size_t)(m0 + wave * 16 + srow) * HH + k0 + sw;
            async_copy16(ag,          As + wave * 1024);
            async_copy16(ag + 8 * HH, As + wave * 1024 + 512);
        }
#pragma unroll
        for (int i = 0; i < 2; ++i) {
            const int c = wave * 2 + i;
            const __hip_bfloat16* bg = Bm + (size_t)(n0 + c * 16 + srow) * HH + k0 + sw;
            async_copy16(bg,          Bs + c * 1024);
            async_copy16(bg + 8 * HH, Bs + c * 1024 + 512);
        }
        __syncthreads();

#pragma unroll
        for (int ks = 0; ks < 64; ks += 16) {
            const int pos = ((((ks >> 3) + ghi) ^ fm7) * 8);
            s16x8 af[2], bf;
#pragma unroll
            for (int mi = 0; mi < 2; ++mi)
                af[mi] = *(const s16x8*)(As + (mi * 32 + fm) * 64 + pos);
            bf = *(const s16x8*)(Bs + (wn + fm) * 64 + pos);
#pragma unroll
            for (int mi = 0; mi < 2; ++mi)
                acc[mi] = __builtin_amdgcn_mfma_f32_32x32x16_bf16(
                    af[mi], bf, acc[mi], 0, 0, 0);
        }
    }

    const int ec = lane & 31;
    const int eb = (lane >> 5) * 4;
#pragma unroll
    for (int mi = 0; mi < 2; ++mi)
#pragma unroll
        for (int r = 0; r < 16; ++r) {
            const int m = m0 + mi * 32 + (r & 3) + 8 * (r >> 2) + eb;
            const int n = n0 + wn + ec;
            store_c(C, (size_t)m * HH + n, acc[mi][r]);
        }
}

// F_b = W2_b @ WqT^T (= W2_b @ Wq), bf16 out: grid (16, 8, 2)
__global__ __launch_bounds__(256) void gemm_f(
    const __hip_bfloat16* __restrict__ W2, const __hip_bfloat16* __restrict__ WqT,
    __hip_bfloat16* __restrict__ F)
{
    __shared__ __align__(16) __hip_bfloat16 As[64 * 64];
    __shared__ __align__(16) __hip_bfloat16 Bs[128 * 64];
    const int b = blockIdx.z;
    gemm_nt_body64_m64(W2 + (size_t)b * HH * HH, WqT, F + (size_t)b * HH * HH,
                       As, Bs, blockIdx.x * 64, blockIdx.y * 128);
}

// out_b = h_b @ F_b^T, fp32 out: grid (32, 8, 2)
__global__ __launch_bounds__(256) void gemm_final(
    const __hip_bfloat16* __restrict__ hb, const __hip_bfloat16* __restrict__ F,
    float* __restrict__ outg)
{
    __shared__ __align__(16) __hip_bfloat16 As[64 * 64];
    __shared__ __align__(16) __hip_bfloat16 Bs[128 * 64];
    const int b = blockIdx.z;
    gemm_nt_body64_m64(hb + (size_t)b * MM * HH, F + (size_t)b * HH * HH,
                       outg + (size_t)b * MM * HH, As, Bs,
                       blockIdx.x * 64, blockIdx.y * 128);
}

// ---------------------------------------------------------------------------
// W2[b][n][h*64+dp] = sum_d Wo[n][h*64+d] * T[b,h,dp,d]   (bf16 out)
// grid (8, KH, BB), block 256  (verified rounds 2-7)
// ---------------------------------------------------------------------------
__global__ __launch_bounds__(256) void w2_fold(
    const __hip_bfloat16* __restrict__ Wo,
    const float* __restrict__ S,
    __hip_bfloat16* __restrict__ W2)
{
    __shared__ float Sl[64 * 68];
    __shared__ float Wl[128 * 68];
    const int t = threadIdx.x, head = blockIdx.y, b = blockIdx.z;
    const int n0 = blockIdx.x * 128;

    const float* Sg = S + ((size_t)b * KH + head) * 4096;
    for (int idx = t; idx < 4096; idx += 256) {
        const int dp = idx >> 6, d = idx & 63;
        Sl[d * 68 + dp] = Sg[idx];
    }
    for (int idx = t; idx < 1024; idx += 256) {
        const int r = idx >> 3, c8 = (idx & 7) * 8;
        s16x8 wv = *(const s16x8*)(Wo + (size_t)(n0 + r) * HH + head * 64 + c8);
#pragma unroll
        for (int j = 0; j < 8; ++j) {
            __hip_bfloat16 wb = *(((const __hip_bfloat16*)&wv) + j);
            Wl[r * 68 + c8 + j] = __bfloat162float(wb);
        }
    }
    __syncthreads();

    const int dpb = (t & 15) * 4;
    const int ng  = t >> 4;
    float acc[8][4] = {};
    for (int d0 = 0; d0 < 64; d0 += 4) {
        f32x4 sv[4];
#pragma unroll
        for (int r = 0; r < 4; ++r)
            sv[r] = *(const f32x4*)(Sl + (d0 + r) * 68 + dpb);
#pragma unroll
        for (int i = 0; i < 8; ++i) {
            const f32x4 wv = *(const f32x4*)(Wl + (ng + 16 * i) * 68 + d0);
#pragma unroll
            for (int r = 0; r < 4; ++r)
#pragma unroll
                for (int j = 0; j < 4; ++j)
                    acc[i][j] += wv[r] * sv[r][j];
        }
    }

#pragma unroll
    for (int i = 0; i < 8; ++i) {
        bf16x4_t o;
        o.x = __float2bfloat16(acc[i][0]);
        o.y = __float2bfloat16(acc[i][1]);
        o.z = __float2bfloat16(acc[i][2]);
        o.w = __float2bfloat16(acc[i][3]);
        *(bf16x4_t*)(W2 + (size_t)b * HH * HH + (size_t)(n0 + ng + 16 * i) * HH
                     + head * 64 + dpb) = o;
    }
}

// ---------------------------------------------------------------------------
extern "C" void kernel_launch(void* const* d_in, const int* in_sizes, int n_in,
                              void* d_out, int out_size, void* d_ws, size_t ws_size,
                              hipStream_t stream) {
    const float* h_f  = (const float*)d_in[0];
    const float* hc_f = (const float*)d_in[1];
    // d_in[2] = key_pe: DEAD (softmax result unused by reference output)
    const float* Wq_f = (const float*)d_in[3];
    const float* Wk_f = (const float*)d_in[4];
    const float* Wv_f = (const float*)d_in[5];
    const float* Wo_f = (const float*)d_in[6];
    float* out = (float*)d_out;

    const size_t act_b = (size_t)BB * MM * HH * 2;  // 8 MB
    const size_t w_b   = (size_t)HH * HH * 2;       // 2 MB
    char* ws = (char*)d_ws;
    __hip_bfloat16* hb   = (__hip_bfloat16*)(ws);                       // 8 MB
    __hip_bfloat16* hcb  = (__hip_bfloat16*)(ws + act_b);               // 8 MB
    __hip_bfloat16* wkb  = (__hip_bfloat16*)(ws + 2 * act_b);           // 2 MB
    __hip_bfloat16* wvb  = (__hip_bfloat16*)(ws + 2 * act_b + w_b);     // 2 MB
    __hip_bfloat16* wob  = (__hip_bfloat16*)(ws + 2 * act_b + 2 * w_b); // 2 MB
    __hip_bfloat16* wqt  = (__hip_bfloat16*)(ws + 2 * act_b + 3 * w_b); // 2 MB
    float*          Sbuf = (float*)(ws + 2 * act_b + 4 * w_b);          // 512 KB
    __hip_bfloat16* W2   = (__hip_bfloat16*)(ws + 2 * act_b + 4 * w_b + (size_t)512 * 1024);  // 4 MB
    __hip_bfloat16* Fbuf = (__hip_bfloat16*)(ws + 2 * act_b + 6 * w_b + (size_t)512 * 1024);  // 4 MB

    const dim3 blk(256);

    // 0: fp32->bf16 converts + Sbuf zeroing; Wq transpose-convert
    cvt6b<<<dim3(4096, 6), blk, 0, stream>>>(h_f, hc_f, Wk_f, Wv_f, Wo_f,
                                             hb, hcb, wkb, wvb, wob, Sbuf);
    transpose_wq<<<dim3(16, 16), blk, 0, stream>>>(Wq_f, wqt);

    // 1: FUSED K/V projection + T = K^T V (atomic partials into zeroed Sbuf)
    gemm_kvt<<<dim3(32, KH), blk, 0, stream>>>(hcb, wkb, wvb, Sbuf);

    // 2: W2 = blockdiag(T) folded into Wo
    w2_fold<<<dim3(8, KH, BB), blk, 0, stream>>>(wob, Sbuf, W2);

    // 3: F = W2 @ Wq (replaces the Q projection: out = h (W2 Wq)^T)
    gemm_f<<<dim3(16, 8, 2), blk, 0, stream>>>(W2, wqt, Fbuf);

    // 4: out = h @ F^T (fp32 out)
    gemm_final<<<dim3(32, 8, 2), blk, 0, stream>>>(hb, Fbuf, out);
}

// Round 9
// 163.536 us; speedup vs baseline: 1.0920x; 1.0194x over previous
//
#include <hip/hip_runtime.h>
#include <hip/hip_bf16.h>

// Problem dims (fixed): B=2, M=L=2048, H=1024, K_HEADS=16, D=64
// All inputs/output are FLOAT32; compute in bf16 MFMA with f32 accumulation.
// Algebra: softmax branch is dead; out = Q (K^T V) blockdiag Wo^T, folded as
//   T_h = K_h^T V_h (per head, 64x64)          [fused into the K/V projection]
//   W2[n][h*64+dp] = sum_d Wo[n][h*64+d] T[h][dp][d]
//   F_b = W2_b @ Wq                            (replaces the Q projection)
//   out_b = h_b @ F_b^T
// Big GEMMs: 32x32x16 bf16 MFMA, BK=64, 8-group XOR-swizzled LDS.
// Round 9: transpose_wq + Sbuf-zero folded into the cvt dispatch (5 dispatches).
#define BB 2
#define MM 2048
#define HH 1024
#define KH 16

typedef short s16x8 __attribute__((ext_vector_type(8)));
typedef float f32x4 __attribute__((ext_vector_type(4)));
typedef float f32x16 __attribute__((ext_vector_type(16)));

#define GLOBAL_AS __attribute__((address_space(1)))
#define LDS_AS    __attribute__((address_space(3)))

__device__ __forceinline__ void async_copy16(const void* g, void* l) {
    __builtin_amdgcn_global_load_lds((const GLOBAL_AS void*)g, (LDS_AS void*)l, 16, 0, 0);
}

struct __align__(8) bf16x4_t { __hip_bfloat16 x, y, z, w; };

// ---------------------------------------------------------------------------
// fused prep: fp32->bf16 converts + Wq transpose + Sbuf zero: grid (4096, 6)
// segs 0-4: convert h, h_cache, Wk, Wv, Wo
// seg 5: bx<128 -> zero Sbuf; 128<=bx<384 -> transpose-convert Wq tile
// ---------------------------------------------------------------------------
__global__ __launch_bounds__(256) void cvt_all(
    const float* __restrict__ s0, const float* __restrict__ s1,
    const float* __restrict__ s2, const float* __restrict__ s3,
    const float* __restrict__ s4, const float* __restrict__ Wq,
    __hip_bfloat16* __restrict__ d0, __hip_bfloat16* __restrict__ d1,
    __hip_bfloat16* __restrict__ d2, __hip_bfloat16* __restrict__ d3,
    __hip_bfloat16* __restrict__ d4, __hip_bfloat16* __restrict__ WqT,
    float* __restrict__ Sz)
{
    const int seg = blockIdx.y;
    const int t = threadIdx.x;
    if (seg == 5) {
        const int bx = blockIdx.x;
        if (bx < 128) {                        // zero Sbuf: 131072 floats
            const int i = (bx * 256 + t) * 4;
            float4 z = {0.f, 0.f, 0.f, 0.f};
            *(float4*)(Sz + i) = z;
        } else if (bx < 384) {                 // transpose Wq tile (64x64)
            __shared__ float Tl[64][65];
            const int tile = bx - 128;
            const int j0 = (tile >> 4) * 64;
            const int k0 = (tile & 15) * 64;
            const int r = t >> 6;
            const int c = t & 63;
#pragma unroll
            for (int i = 0; i < 64; i += 4)
                Tl[r + i][c] = Wq[(size_t)(j0 + r + i) * HH + k0 + c];
            __syncthreads();
#pragma unroll
            for (int i = 0; i < 64; i += 4)
                WqT[(size_t)(k0 + r + i) * HH + j0 + c] = __float2bfloat16(Tl[c][r + i]);
        }
        return;
    }
    const float* src;
    __hip_bfloat16* dst;
    int n;
    switch (seg) {
        case 0: src = s0; dst = d0; n = BB * MM * HH; break;
        case 1: src = s1; dst = d1; n = BB * MM * HH; break;
        case 2: src = s2; dst = d2; n = HH * HH; break;
        case 3: src = s3; dst = d3; n = HH * HH; break;
        default: src = s4; dst = d4; n = HH * HH; break;
    }
    const int i = (blockIdx.x * 256 + t) * 4;
    if (i + 3 < n) {
        const float4 v = *(const float4*)(src + i);
        bf16x4_t o;
        o.x = __float2bfloat16(v.x);
        o.y = __float2bfloat16(v.y);
        o.z = __float2bfloat16(v.z);
        o.w = __float2bfloat16(v.w);
        *(bf16x4_t*)(dst + i) = o;
    }
}

// ---------------------------------------------------------------------------
// store helpers
// ---------------------------------------------------------------------------
__device__ __forceinline__ void store_c(__hip_bfloat16* C, size_t idx, float v) {
    C[idx] = __float2bfloat16(v);
}
__device__ __forceinline__ void store_c(float* C, size_t idx, float v) { C[idx] = v; }

// ---------------------------------------------------------------------------
// FUSED K/V projection + T = K^T V   (grid (32 l-tiles, 16 heads) = 512 blks)
// Phase 1: K-tile[128x64] = hcb_tile @ Wk_h^T, V-tile likewise — A staged once,
//          BK=64, XOR-swizzled LDS, 32x32x16 MFMA, K/V stay in registers.
// Phase 2: acc -> bf16 -> LDS [d][l] (stride 136), T-MFMA (16x16x32) + atomics.
// (verified round 8)
// ---------------------------------------------------------------------------
#define LP2 136

__global__ __launch_bounds__(256) void gemm_kvt(
    const __hip_bfloat16* __restrict__ hcb,
    const __hip_bfloat16* __restrict__ wk, const __hip_bfloat16* __restrict__ wv,
    float* __restrict__ S)
{
    __shared__ __align__(16) char smem[64 * LP2 * 2 * 2];  // 34816 B
    __hip_bfloat16* As  = (__hip_bfloat16*)smem;            // 16 KB (128x64)
    __hip_bfloat16* Bsk = (__hip_bfloat16*)(smem + 16384);  //  8 KB (64x64)
    __hip_bfloat16* Bsv = (__hip_bfloat16*)(smem + 24576);  //  8 KB (64x64)
    __hip_bfloat16* Kt  = (__hip_bfloat16*)smem;            // 17408 B (64xLP2)
    __hip_bfloat16* Vt  = (__hip_bfloat16*)(smem + 64 * LP2 * 2);

    const int t    = threadIdx.x;
    const int lane = t & 63;
    const int wave = t >> 6;
    const int head = blockIdx.y;
    const int m0   = blockIdx.x * 128;
    const int n0   = head * 64;
    const int b    = blockIdx.x >> 4;

    const int srow = lane >> 3;
    const int sw   = ((lane & 7) ^ srow) * 8;

    const int wm  = (wave >> 1) * 64;
    const int wn  = (wave & 1) * 32;
    const int fm  = lane & 31;
    const int fm7 = fm & 7;
    const int ghi = lane >> 5;

    f32x16 acck[2] = {};
    f32x16 accv[2] = {};

    for (int k0 = 0; k0 < HH; k0 += 64) {
        __syncthreads();
#pragma unroll
        for (int i = 0; i < 4; ++i) {
            const int c = wave * 4 + i;
            async_copy16(hcb + (size_t)(m0 + c * 8 + srow) * HH + k0 + sw,
                         As + c * 512);
        }
#pragma unroll
        for (int i = 0; i < 2; ++i) {
            const int c = wave * 2 + i;
            async_copy16(wk + (size_t)(n0 + c * 8 + srow) * HH + k0 + sw,
                         Bsk + c * 512);
            async_copy16(wv + (size_t)(n0 + c * 8 + srow) * HH + k0 + sw,
                         Bsv + c * 512);
        }
        __syncthreads();

#pragma unroll
        for (int ks = 0; ks < 64; ks += 16) {
            const int pos = ((((ks >> 3) + ghi) ^ fm7) * 8);
            s16x8 af[2];
#pragma unroll
            for (int mi = 0; mi < 2; ++mi)
                af[mi] = *(const s16x8*)(As + (wm + mi * 32 + fm) * 64 + pos);
            const s16x8 bk = *(const s16x8*)(Bsk + (wn + fm) * 64 + pos);
            const s16x8 bv = *(const s16x8*)(Bsv + (wn + fm) * 64 + pos);
#pragma unroll
            for (int mi = 0; mi < 2; ++mi) {
                acck[mi] = __builtin_amdgcn_mfma_f32_32x32x16_bf16(af[mi], bk, acck[mi], 0, 0, 0);
                accv[mi] = __builtin_amdgcn_mfma_f32_32x32x16_bf16(af[mi], bv, accv[mi], 0, 0, 0);
            }
        }
    }

    __syncthreads();

    const int dcol = wn + (lane & 31);
    const int lhi  = 4 * (lane >> 5);
#pragma unroll
    for (int mi = 0; mi < 2; ++mi)
#pragma unroll
        for (int g = 0; g < 4; ++g) {
            const int lb = wm + mi * 32 + 8 * g + lhi;
            bf16x4_t ok, ov;
            ok.x = __float2bfloat16(acck[mi][4 * g + 0]);
            ok.y = __float2bfloat16(acck[mi][4 * g + 1]);
            ok.z = __float2bfloat16(acck[mi][4 * g + 2]);
            ok.w = __float2bfloat16(acck[mi][4 * g + 3]);
            ov.x = __float2bfloat16(accv[mi][4 * g + 0]);
            ov.y = __float2bfloat16(accv[mi][4 * g + 1]);
            ov.z = __float2bfloat16(accv[mi][4 * g + 2]);
            ov.w = __float2bfloat16(accv[mi][4 * g + 3]);
            *(bf16x4_t*)(Kt + dcol * LP2 + lb) = ok;
            *(bf16x4_t*)(Vt + dcol * LP2 + lb) = ov;
        }
    __syncthreads();

    const int fr = lane & 15;
    const int fq = (lane >> 4) * 8;
    const int wm2 = wave * 16;

    f32x4 acc2[4] = {};
#pragma unroll
    for (int kk = 0; kk < 128; kk += 32) {
        const s16x8 af = *(const s16x8*)(Kt + (wm2 + fr) * LP2 + kk + fq);
        s16x8 bf[4];
#pragma unroll
        for (int nj = 0; nj < 4; ++nj)
            bf[nj] = *(const s16x8*)(Vt + (nj * 16 + fr) * LP2 + kk + fq);
#pragma unroll
        for (int nj = 0; nj < 4; ++nj)
            acc2[nj] = __builtin_amdgcn_mfma_f32_16x16x32_bf16(af, bf[nj], acc2[nj], 0, 0, 0);
    }

    float* Sg = S + ((size_t)b * KH + head) * 4096;
    const int er = (lane >> 4) * 4;
    const int ec = lane & 15;
#pragma unroll
    for (int nj = 0; nj < 4; ++nj)
#pragma unroll
        for (int rr = 0; rr < 4; ++rr)
            atomicAdd(&Sg[(wm2 + er + rr) * 64 + nj * 16 + ec], acc2[nj][rr]);
}

// ---------------------------------------------------------------------------
// 64x128-tile BK=64 NT GEMM body (verified rounds 7-8)
// ---------------------------------------------------------------------------
template <typename OutT>
__device__ __forceinline__ void gemm_nt_body64_m64(
    const __hip_bfloat16* __restrict__ A,
    const __hip_bfloat16* __restrict__ Bm,
    OutT* __restrict__ C,
    __hip_bfloat16* As, __hip_bfloat16* Bs,
    int m0, int n0)
{
    const int t    = threadIdx.x;
    const int lane = t & 63;
    const int wave = t >> 6;

    const int srow = lane >> 3;
    const int sw   = ((lane & 7) ^ srow) * 8;

    const int wn  = wave * 32;
    const int fm  = lane & 31;
    const int fm7 = fm & 7;
    const int ghi = lane >> 5;

    f32x16 acc[2] = {};

    for (int k0 = 0; k0 < HH; k0 += 64) {
        __syncthreads();
        {
            const __hip_bfloat16* ag = A + (size_t)(m0 + wave * 16 + srow) * HH + k0 + sw;
            async_copy16(ag,          As + wave * 1024);
            async_copy16(ag + 8 * HH, As + wave * 1024 + 512);
        }
#pragma unroll
        for (int i = 0; i < 2; ++i) {
            const int c = wave * 2 + i;
            const __hip_bfloat16* bg = Bm + (size_t)(n0 + c * 16 + srow) * HH + k0 + sw;
            async_copy16(bg,          Bs + c * 1024);
            async_copy16(bg + 8 * HH, Bs + c * 1024 + 512);
        }
        __syncthreads();

#pragma unroll
        for (int ks = 0; ks < 64; ks += 16) {
            const int pos = ((((ks >> 3) + ghi) ^ fm7) * 8);
            s16x8 af[2], bf;
#pragma unroll
            for (int mi = 0; mi < 2; ++mi)
                af[mi] = *(const s16x8*)(As + (mi * 32 + fm) * 64 + pos);
            bf = *(const s16x8*)(Bs + (wn + fm) * 64 + pos);
#pragma unroll
            for (int mi = 0; mi < 2; ++mi)
                acc[mi] = __builtin_amdgcn_mfma_f32_32x32x16_bf16(
                    af[mi], bf, acc[mi], 0, 0, 0);
        }
    }

    const int ec = lane & 31;
    const int eb = (lane >> 5) * 4;
#pragma unroll
    for (int mi = 0; mi < 2; ++mi)
#pragma unroll
        for (int r = 0; r < 16; ++r) {
            const int m = m0 + mi * 32 + (r & 3) + 8 * (r >> 2) + eb;
            const int n = n0 + wn + ec;
            store_c(C, (size_t)m * HH + n, acc[mi][r]);
        }
}

// F_b = W2_b @ WqT^T (= W2_b @ Wq), bf16 out: grid (16, 8, 2)
__global__ __launch_bounds__(256) void gemm_f(
    const __hip_bfloat16* __restrict__ W2, const __hip_bfloat16* __restrict__ WqT,
    __hip_bfloat16* __restrict__ F)
{
    __shared__ __align__(16) __hip_bfloat16 As[64 * 64];
    __shared__ __align__(16) __hip_bfloat16 Bs[128 * 64];
    const int b = blockIdx.z;
    gemm_nt_body64_m64(W2 + (size_t)b * HH * HH, WqT, F + (size_t)b * HH * HH,
                       As, Bs, blockIdx.x * 64, blockIdx.y * 128);
}

// out_b = h_b @ F_b^T, fp32 out: grid (32, 8, 2)
__global__ __launch_bounds__(256) void gemm_final(
    const __hip_bfloat16* __restrict__ hb, const __hip_bfloat16* __restrict__ F,
    float* __restrict__ outg)
{
    __shared__ __align__(16) __hip_bfloat16 As[64 * 64];
    __shared__ __align__(16) __hip_bfloat16 Bs[128 * 64];
    const int b = blockIdx.z;
    gemm_nt_body64_m64(hb + (size_t)b * MM * HH, F + (size_t)b * HH * HH,
                       outg + (size_t)b * MM * HH, As, Bs,
                       blockIdx.x * 64, blockIdx.y * 128);
}

// ---------------------------------------------------------------------------
// W2[b][n][h*64+dp] = sum_d Wo[n][h*64+d] * T[b,h,dp,d]   (bf16 out)
// grid (8, KH, BB), block 256  (verified rounds 2-8)
// ---------------------------------------------------------------------------
__global__ __launch_bounds__(256) void w2_fold(
    const __hip_bfloat16* __restrict__ Wo,
    const float* __restrict__ S,
    __hip_bfloat16* __restrict__ W2)
{
    __shared__ float Sl[64 * 68];
    __shared__ float Wl[128 * 68];
    const int t = threadIdx.x, head = blockIdx.y, b = blockIdx.z;
    const int n0 = blockIdx.x * 128;

    const float* Sg = S + ((size_t)b * KH + head) * 4096;
    for (int idx = t; idx < 4096; idx += 256) {
        const int dp = idx >> 6, d = idx & 63;
        Sl[d * 68 + dp] = Sg[idx];
    }
    for (int idx = t; idx < 1024; idx += 256) {
        const int r = idx >> 3, c8 = (idx & 7) * 8;
        s16x8 wv = *(const s16x8*)(Wo + (size_t)(n0 + r) * HH + head * 64 + c8);
#pragma unroll
        for (int j = 0; j < 8; ++j) {
            __hip_bfloat16 wb = *(((const __hip_bfloat16*)&wv) + j);
            Wl[r * 68 + c8 + j] = __bfloat162float(wb);
        }
    }
    __syncthreads();

    const int dpb = (t & 15) * 4;
    const int ng  = t >> 4;
    float acc[8][4] = {};
    for (int d0 = 0; d0 < 64; d0 += 4) {
        f32x4 sv[4];
#pragma unroll
        for (int r = 0; r < 4; ++r)
            sv[r] = *(const f32x4*)(Sl + (d0 + r) * 68 + dpb);
#pragma unroll
        for (int i = 0; i < 8; ++i) {
            const f32x4 wv = *(const f32x4*)(Wl + (ng + 16 * i) * 68 + d0);
#pragma unroll
            for (int r = 0; r < 4; ++r)
#pragma unroll
                for (int j = 0; j < 4; ++j)
                    acc[i][j] += wv[r] * sv[r][j];
        }
    }

#pragma unroll
    for (int i = 0; i < 8; ++i) {
        bf16x4_t o;
        o.x = __float2bfloat16(acc[i][0]);
        o.y = __float2bfloat16(acc[i][1]);
        o.z = __float2bfloat16(acc[i][2]);
        o.w = __float2bfloat16(acc[i][3]);
        *(bf16x4_t*)(W2 + (size_t)b * HH * HH + (size_t)(n0 + ng + 16 * i) * HH
                     + head * 64 + dpb) = o;
    }
}

// ---------------------------------------------------------------------------
extern "C" void kernel_launch(void* const* d_in, const int* in_sizes, int n_in,
                              void* d_out, int out_size, void* d_ws, size_t ws_size,
                              hipStream_t stream) {
    const float* h_f  = (const float*)d_in[0];
    const float* hc_f = (const float*)d_in[1];
    // d_in[2] = key_pe: DEAD (softmax result unused by reference output)
    const float* Wq_f = (const float*)d_in[3];
    const float* Wk_f = (const float*)d_in[4];
    const float* Wv_f = (const float*)d_in[5];
    const float* Wo_f = (const float*)d_in[6];
    float* out = (float*)d_out;

    const size_t act_b = (size_t)BB * MM * HH * 2;  // 8 MB
    const size_t w_b   = (size_t)HH * HH * 2;       // 2 MB
    char* ws = (char*)d_ws;
    __hip_bfloat16* hb   = (__hip_bfloat16*)(ws);                       // 8 MB
    __hip_bfloat16* hcb  = (__hip_bfloat16*)(ws + act_b);               // 8 MB
    __hip_bfloat16* wkb  = (__hip_bfloat16*)(ws + 2 * act_b);           // 2 MB
    __hip_bfloat16* wvb  = (__hip_bfloat16*)(ws + 2 * act_b + w_b);     // 2 MB
    __hip_bfloat16* wob  = (__hip_bfloat16*)(ws + 2 * act_b + 2 * w_b); // 2 MB
    __hip_bfloat16* wqt  = (__hip_bfloat16*)(ws + 2 * act_b + 3 * w_b); // 2 MB
    float*          Sbuf = (float*)(ws + 2 * act_b + 4 * w_b);          // 512 KB
    __hip_bfloat16* W2   = (__hip_bfloat16*)(ws + 2 * act_b + 4 * w_b + (size_t)512 * 1024);  // 4 MB
    __hip_bfloat16* Fbuf = (__hip_bfloat16*)(ws + 2 * act_b + 6 * w_b + (size_t)512 * 1024);  // 4 MB

    const dim3 blk(256);

    // 0: all prep in one dispatch (converts + Wq transpose + Sbuf zero)
    cvt_all<<<dim3(4096, 6), blk, 0, stream>>>(h_f, hc_f, Wk_f, Wv_f, Wo_f, Wq_f,
                                               hb, hcb, wkb, wvb, wob, wqt, Sbuf);

    // 1: FUSED K/V projection + T = K^T V (atomic partials into zeroed Sbuf)
    gemm_kvt<<<dim3(32, KH), blk, 0, stream>>>(hcb, wkb, wvb, Sbuf);

    // 2: W2 = blockdiag(T) folded into Wo
    w2_fold<<<dim3(8, KH, BB), blk, 0, stream>>>(wob, Sbuf, W2);

    // 3: F = W2 @ Wq (replaces the Q projection: out = h (W2 Wq)^T)
    gemm_f<<<dim3(16, 8, 2), blk, 0, stream>>>(W2, wqt, Fbuf);

    // 4: out = h @ F^T (fp32 out)
    gemm_final<<<dim3(32, 8, 2), blk, 0, stream>>>(hb, Fbuf, out);
}